// Round 1
// baseline (846.237 us; speedup 1.0000x reference)
//
#include <hip/hip_runtime.h>
#include <math.h>

#define F_IN 128
#define HID  256
#define CLS  40

// ---------------- edge_index decode (int32 vs int64 hedge) ----------------
// If the buffer is int64 ([2,E] little-endian, values < 2^31), every odd
// int32 word is the zero high-half. With real int32 data those words are
// random node ids in [0,100000) -> P(all zero) ~ 0.
__global__ void detect_kernel(const int* __restrict__ ei, int* __restrict__ flag) {
  if (threadIdx.x == 0 && blockIdx.x == 0) {
    int ornz = 0;
    for (int i = 1; i < 256; i += 2) ornz |= ei[i];
    *flag = (ornz == 0) ? 1 : 0;
  }
}

__device__ __forceinline__ int edge_dst(const int* ei, int e, int E, int is64) {
  return is64 ? ei[2ll * E + 2ll * e] : ei[(long long)E + e];
}
__device__ __forceinline__ int edge_src(const int* ei, int e, int is64) {
  return is64 ? ei[2ll * e] : ei[e];
}

// ---------------- CSR build ----------------
__global__ __launch_bounds__(256) void hist_kernel(const int* __restrict__ ei, int E,
                                                   const int* __restrict__ flag,
                                                   int* __restrict__ cnt) {
  int e = blockIdx.x * 256 + threadIdx.x;
  if (e < E) {
    int is64 = *flag;
    int d = edge_dst(ei, e, E, is64);
    atomicAdd(&cnt[d], 1);
  }
}

__global__ __launch_bounds__(256) void blocksum_kernel(const int* __restrict__ cnt,
                                                       int* __restrict__ bsum, int n) {
  __shared__ int s[256];
  int t = threadIdx.x;
  int i = blockIdx.x * 256 + t;
  s[t] = (i < n) ? cnt[i] : 0;
  __syncthreads();
  for (int d = 128; d > 0; d >>= 1) {
    if (t < d) s[t] += s[t + d];
    __syncthreads();
  }
  if (t == 0) bsum[blockIdx.x] = s[0];
}

// single-block exclusive scan of block sums (nb <= 512)
__global__ __launch_bounds__(512) void scan_bsum_kernel(int* __restrict__ bsum, int nb) {
  __shared__ int s[512];
  int t = threadIdx.x;
  int v = (t < nb) ? bsum[t] : 0;
  s[t] = v;
  __syncthreads();
  for (int d = 1; d < 512; d <<= 1) {
    int xv = (t >= d) ? s[t - d] : 0;
    __syncthreads();
    s[t] += xv;
    __syncthreads();
  }
  if (t < nb) bsum[t] = s[t] - v;  // exclusive
}

__global__ __launch_bounds__(256) void scan_apply_kernel(const int* __restrict__ cnt,
                                                         const int* __restrict__ bsum,
                                                         int* __restrict__ rowptr,
                                                         int* __restrict__ cursor,
                                                         int N, int E) {
  __shared__ int s[256];
  int t = threadIdx.x;
  int i = blockIdx.x * 256 + t;
  int v = (i < N) ? cnt[i] : 0;
  s[t] = v;
  __syncthreads();
  for (int d = 1; d < 256; d <<= 1) {
    int xv = (t >= d) ? s[t - d] : 0;
    __syncthreads();
    s[t] += xv;
    __syncthreads();
  }
  int excl = s[t] - v + bsum[blockIdx.x];
  if (i < N) {
    rowptr[i] = excl;
    cursor[i] = excl;
  }
  if (i == N - 1) rowptr[N] = E;
}

__global__ __launch_bounds__(256) void scatter_kernel(const int* __restrict__ ei, int E,
                                                      const int* __restrict__ flag,
                                                      int* __restrict__ cursor,
                                                      int* __restrict__ csr_col) {
  int e = blockIdx.x * 256 + threadIdx.x;
  if (e < E) {
    int is64 = *flag;
    int d = edge_dst(ei, e, E, is64);
    int sv = edge_src(ei, e, is64);
    int pos = atomicAdd(&cursor[d], 1);
    csr_col[pos] = sv;
  }
}

// ---------------- layer-1 mean aggregation: one wave per dst row ----------------
__global__ __launch_bounds__(256) void agg1_kernel(const float* __restrict__ x,
                                                   const int* __restrict__ rowptr,
                                                   const int* __restrict__ col,
                                                   float* __restrict__ agg, int N) {
  int wave = threadIdx.x >> 6, lane = threadIdx.x & 63;
  int row = blockIdx.x * 4 + wave;
  if (row >= N) return;
  int s0 = rowptr[row], s1 = rowptr[row + 1];
  float ax = 0.f, ay = 0.f;
  int j = s0;
  for (; j + 1 < s1; j += 2) {
    int c0 = col[j], c1 = col[j + 1];
    float2 v0 = *(const float2*)(x + (size_t)c0 * F_IN + lane * 2);
    float2 v1 = *(const float2*)(x + (size_t)c1 * F_IN + lane * 2);
    ax += v0.x + v1.x;
    ay += v0.y + v1.y;
  }
  if (j < s1) {
    int c0 = col[j];
    float2 v0 = *(const float2*)(x + (size_t)c0 * F_IN + lane * 2);
    ax += v0.x;
    ay += v0.y;
  }
  float inv = 1.f / fmaxf((float)(s1 - s0), 1.f);
  float2 o;
  o.x = ax * inv;
  o.y = ay * inv;
  *(float2*)(agg + (size_t)row * F_IN + lane * 2) = o;
}

// ---------------- GEMM1: h = relu([agg|x] @ [W1l;W1r] + b1) ----------------
// M x 256(K) x 256(N), fp32 vector FMA. BM=64, BN=256, BK=32, 8x8 per thread.
__global__ __launch_bounds__(256) void gemm1_kernel(const float* __restrict__ agg,
                                                    const float* __restrict__ x,
                                                    const float* __restrict__ W1l,
                                                    const float* __restrict__ W1r,
                                                    const float* __restrict__ b1,
                                                    float* __restrict__ h, int M) {
  __shared__ float Alds[32][64];    // transposed: Alds[k][row]
  __shared__ float Blds[32][256];   // Blds[k][n]
  int t = threadIdx.x;
  int tx = t & 31, ty = t >> 5;
  int row0 = blockIdx.x * 64;
  float acc[8][8] = {};
  int ar = t >> 2;          // 0..63 : row this thread stages
  int ak = (t & 3) * 8;     // 0,8,16,24 : k-offset this thread stages

  for (int k0 = 0; k0 < 256; k0 += 32) {
    const float* Asrc = (k0 < 128) ? (agg + k0) : (x + (k0 - 128));
    int grow = row0 + ar;
    float4 a0 = {0, 0, 0, 0}, a1 = {0, 0, 0, 0};
    if (grow < M) {
      const float* ap = Asrc + (size_t)grow * F_IN + ak;
      a0 = *(const float4*)ap;
      a1 = *(const float4*)(ap + 4);
    }
    float4 bv[8];
#pragma unroll
    for (int i = 0; i < 8; ++i) {
      int f = i * 256 + t;
      int k = f >> 6, n4 = f & 63;
      int kg = k0 + k;
      const float* Bsrc = (kg < 128) ? (W1l + (size_t)kg * HID)
                                     : (W1r + (size_t)(kg - 128) * HID);
      bv[i] = *(const float4*)(Bsrc + n4 * 4);
    }
    __syncthreads();
    Alds[ak + 0][ar] = a0.x;
    Alds[ak + 1][ar] = a0.y;
    Alds[ak + 2][ar] = a0.z;
    Alds[ak + 3][ar] = a0.w;
    Alds[ak + 4][ar] = a1.x;
    Alds[ak + 5][ar] = a1.y;
    Alds[ak + 6][ar] = a1.z;
    Alds[ak + 7][ar] = a1.w;
#pragma unroll
    for (int i = 0; i < 8; ++i) {
      int f = i * 256 + t;
      int k = f >> 6, n4 = f & 63;
      *(float4*)&Blds[k][n4 * 4] = bv[i];
    }
    __syncthreads();
#pragma unroll
    for (int kk = 0; kk < 32; ++kk) {
      float4 a0v = *(const float4*)&Alds[kk][ty * 8];
      float4 a1v = *(const float4*)&Alds[kk][ty * 8 + 4];
      float4 b0v = *(const float4*)&Blds[kk][tx * 8];
      float4 b1v = *(const float4*)&Blds[kk][tx * 8 + 4];
      float av[8] = {a0v.x, a0v.y, a0v.z, a0v.w, a1v.x, a1v.y, a1v.z, a1v.w};
      float bw[8] = {b0v.x, b0v.y, b0v.z, b0v.w, b1v.x, b1v.y, b1v.z, b1v.w};
#pragma unroll
      for (int i = 0; i < 8; ++i)
#pragma unroll
        for (int jj = 0; jj < 8; ++jj)
          acc[i][jj] = fmaf(av[i], bw[jj], acc[i][jj]);
    }
  }
  float bias[8];
#pragma unroll
  for (int jj = 0; jj < 8; ++jj) bias[jj] = b1[tx * 8 + jj];
#pragma unroll
  for (int i = 0; i < 8; ++i) {
    int r = row0 + ty * 8 + i;
    if (r < M) {
      float4 o0, o1;
      o0.x = fmaxf(acc[i][0] + bias[0], 0.f);
      o0.y = fmaxf(acc[i][1] + bias[1], 0.f);
      o0.z = fmaxf(acc[i][2] + bias[2], 0.f);
      o0.w = fmaxf(acc[i][3] + bias[3], 0.f);
      o1.x = fmaxf(acc[i][4] + bias[4], 0.f);
      o1.y = fmaxf(acc[i][5] + bias[5], 0.f);
      o1.z = fmaxf(acc[i][6] + bias[6], 0.f);
      o1.w = fmaxf(acc[i][7] + bias[7], 0.f);
      *(float4*)(h + (size_t)r * HID + tx * 8) = o0;
      *(float4*)(h + (size_t)r * HID + tx * 8 + 4) = o1;
    }
  }
}

// ---------------- GEMM2: pr = h @ [W2l|W2r]  (M x 256 x 80) ----------------
// pr[:,0:40] = p = h@W2l (to be aggregated), pr[:,40:80] = r = h@W2r (self term)
__global__ __launch_bounds__(256) void gemm2_kernel(const float* __restrict__ h,
                                                    const float* __restrict__ W2l,
                                                    const float* __restrict__ W2r,
                                                    float* __restrict__ pr, int M) {
  __shared__ float Alds[32][64];   // transposed
  __shared__ float Blds[32][80];
  int t = threadIdx.x;
  int tx = t & 15, ty = t >> 4;   // 16x16 threads: 4 rows x 5 cols each
  int row0 = blockIdx.x * 64;
  float acc[4][5] = {};
  int ar = t >> 2;
  int ak = (t & 3) * 8;

  for (int k0 = 0; k0 < 256; k0 += 32) {
    int grow = row0 + ar;
    float4 a0 = {0, 0, 0, 0}, a1 = {0, 0, 0, 0};
    if (grow < M) {
      const float* ap = h + (size_t)grow * HID + k0 + ak;
      a0 = *(const float4*)ap;
      a1 = *(const float4*)(ap + 4);
    }
    float bvals[10];
#pragma unroll
    for (int i = 0; i < 10; ++i) {
      int f = i * 256 + t;
      int k = f / 80, n = f - k * 80;
      int kg = k0 + k;
      bvals[i] = (n < CLS) ? W2l[(size_t)kg * CLS + n]
                           : W2r[(size_t)kg * CLS + (n - CLS)];
    }
    __syncthreads();
    Alds[ak + 0][ar] = a0.x;
    Alds[ak + 1][ar] = a0.y;
    Alds[ak + 2][ar] = a0.z;
    Alds[ak + 3][ar] = a0.w;
    Alds[ak + 4][ar] = a1.x;
    Alds[ak + 5][ar] = a1.y;
    Alds[ak + 6][ar] = a1.z;
    Alds[ak + 7][ar] = a1.w;
#pragma unroll
    for (int i = 0; i < 10; ++i) {
      int f = i * 256 + t;
      int k = f / 80, n = f - k * 80;
      Blds[k][n] = bvals[i];
    }
    __syncthreads();
#pragma unroll
    for (int kk = 0; kk < 32; ++kk) {
      float4 a0v = *(const float4*)&Alds[kk][ty * 4];
      float av[4] = {a0v.x, a0v.y, a0v.z, a0v.w};
      float bw[5];
#pragma unroll
      for (int jj = 0; jj < 5; ++jj) bw[jj] = Blds[kk][tx * 5 + jj];
#pragma unroll
      for (int i = 0; i < 4; ++i)
#pragma unroll
        for (int jj = 0; jj < 5; ++jj)
          acc[i][jj] = fmaf(av[i], bw[jj], acc[i][jj]);
    }
  }
#pragma unroll
  for (int i = 0; i < 4; ++i) {
    int r = row0 + ty * 4 + i;
    if (r < M) {
#pragma unroll
      for (int jj = 0; jj < 5; ++jj)
        pr[(size_t)r * 80 + tx * 5 + jj] = acc[i][jj];
    }
  }
}

// ---------------- final: mean-aggregate p, add r + b2, log_softmax ----------------
__global__ __launch_bounds__(256) void final_kernel(const int* __restrict__ rowptr,
                                                    const int* __restrict__ col,
                                                    const float* __restrict__ pr,
                                                    const float* __restrict__ b2,
                                                    float* __restrict__ out, int N) {
  int wave = threadIdx.x >> 6, lane = threadIdx.x & 63;
  int row = blockIdx.x * 4 + wave;
  if (row >= N) return;
  int s0 = rowptr[row], s1 = rowptr[row + 1];
  bool active = lane < CLS;
  float acc = 0.f;
  for (int j = s0; j < s1; ++j) {
    int c = col[j];
    if (active) acc += pr[(size_t)c * 80 + lane];
  }
  float inv = 1.f / fmaxf((float)(s1 - s0), 1.f);
  float v = active ? (acc * inv + pr[(size_t)row * 80 + CLS + lane] + b2[lane])
                   : -1e30f;
  float mx = v;
#pragma unroll
  for (int d = 32; d >= 1; d >>= 1) mx = fmaxf(mx, __shfl_xor(mx, d, 64));
  float ex = active ? expf(v - mx) : 0.f;
  float sum = ex;
#pragma unroll
  for (int d = 32; d >= 1; d >>= 1) sum += __shfl_xor(sum, d, 64);
  if (active) out[(size_t)row * CLS + lane] = v - mx - logf(sum);
}

// ---------------- host launcher ----------------
extern "C" void kernel_launch(void* const* d_in, const int* in_sizes, int n_in,
                              void* d_out, int out_size, void* d_ws, size_t ws_size,
                              hipStream_t stream) {
  (void)n_in; (void)out_size; (void)ws_size;
  const float* x   = (const float*)d_in[0];
  const int*   ei  = (const int*)d_in[1];
  const float* W1l = (const float*)d_in[2];
  const float* W1r = (const float*)d_in[3];
  const float* b1  = (const float*)d_in[4];
  const float* W2l = (const float*)d_in[5];
  const float* W2r = (const float*)d_in[6];
  const float* b2  = (const float*)d_in[7];
  float* out = (float*)d_out;

  const int N = in_sizes[0] / F_IN;
  const int E = in_sizes[1] / 2;

  char* ws = (char*)d_ws;
  size_t off = 0;
  auto alloc = [&](size_t bytes) -> void* {
    void* p = ws + off;
    off = (off + bytes + 255) & ~(size_t)255;
    return p;
  };
  int* flag    = (int*)alloc(4);
  int* cnt     = (int*)alloc((size_t)N * 4);
  int* bsum    = (int*)alloc(4096);
  int* rowptr  = (int*)alloc(((size_t)N + 1) * 4);
  int* cursor  = (int*)alloc((size_t)N * 4);
  int* csr_col = (int*)alloc((size_t)E * 4);
  float* h     = (float*)alloc((size_t)N * HID * 4);
  // agg1 (N*128 f32) is dead after gemm1; pr (N*80 f32) reuses its space.
  float* agg   = (float*)alloc((size_t)N * F_IN * 4);
  float* pr    = agg;

  hipMemsetAsync(cnt, 0, (size_t)N * 4, stream);
  detect_kernel<<<1, 64, 0, stream>>>(ei, flag);

  int eb = (E + 255) / 256;
  int nb = (N + 255) / 256;  // 391 <= 512 required by scan_bsum_kernel
  hist_kernel<<<eb, 256, 0, stream>>>(ei, E, flag, cnt);
  blocksum_kernel<<<nb, 256, 0, stream>>>(cnt, bsum, N);
  scan_bsum_kernel<<<1, 512, 0, stream>>>(bsum, nb);
  scan_apply_kernel<<<nb, 256, 0, stream>>>(cnt, bsum, rowptr, cursor, N, E);
  scatter_kernel<<<eb, 256, 0, stream>>>(ei, E, flag, cursor, csr_col);

  agg1_kernel<<<(N + 3) / 4, 256, 0, stream>>>(x, rowptr, csr_col, agg, N);

  int mb = (N + 63) / 64;
  gemm1_kernel<<<mb, 256, 0, stream>>>(agg, x, W1l, W1r, b1, h, N);
  gemm2_kernel<<<mb, 256, 0, stream>>>(h, W2l, W2r, pr, N);
  final_kernel<<<(N + 3) / 4, 256, 0, stream>>>(rowptr, csr_col, pr, b2, out, N);
}

// Round 2
// 537.720 us; speedup vs baseline: 1.5737x; 1.5737x over previous
//
#include <hip/hip_runtime.h>
#include <math.h>

#define F_IN 128
#define HID  256
#define CLS  40

typedef __attribute__((ext_vector_type(8))) short short8v;   // 8 bf16 (4 VGPRs)
typedef __attribute__((ext_vector_type(4))) float f32x4;

#define GLB_AS(p) ((const __attribute__((address_space(1))) unsigned int*)(p))
#define LDS_AS(p) ((__attribute__((address_space(3))) unsigned int*)(p))

__device__ __forceinline__ float bf2f(unsigned short u) {
  unsigned int v = ((unsigned int)u) << 16;
  return __builtin_bit_cast(float, v);
}
__device__ __forceinline__ unsigned short f2bf(float f) {  // round-to-nearest-even
  unsigned int u = __builtin_bit_cast(unsigned int, f);
  u += 0x7fffu + ((u >> 16) & 1u);
  return (unsigned short)(u >> 16);
}

// ---------------- edge_index decode (int32 vs int64 hedge) ----------------
__global__ void detect_kernel(const int* __restrict__ ei, int* __restrict__ flag) {
  if (threadIdx.x == 0 && blockIdx.x == 0) {
    int ornz = 0;
    for (int i = 1; i < 256; i += 2) ornz |= ei[i];
    *flag = (ornz == 0) ? 1 : 0;
  }
}
__device__ __forceinline__ int edge_dst(const int* ei, int e, int E, int is64) {
  return is64 ? ei[2ll * E + 2ll * e] : ei[(long long)E + e];
}
__device__ __forceinline__ int edge_src(const int* ei, int e, int is64) {
  return is64 ? ei[2ll * e] : ei[e];
}

// ---------------- CSR build ----------------
__global__ __launch_bounds__(256) void hist_kernel(const int* __restrict__ ei, int E,
                                                   const int* __restrict__ flag,
                                                   int* __restrict__ cnt) {
  int e = blockIdx.x * 256 + threadIdx.x;
  if (e < E) {
    int is64 = *flag;
    atomicAdd(&cnt[edge_dst(ei, e, E, is64)], 1);
  }
}

__global__ __launch_bounds__(256) void blocksum_kernel(const int* __restrict__ cnt,
                                                       int* __restrict__ bsum, int n) {
  __shared__ int s[256];
  int t = threadIdx.x;
  int i = blockIdx.x * 256 + t;
  s[t] = (i < n) ? cnt[i] : 0;
  __syncthreads();
  for (int d = 128; d > 0; d >>= 1) {
    if (t < d) s[t] += s[t + d];
    __syncthreads();
  }
  if (t == 0) bsum[blockIdx.x] = s[0];
}

__global__ __launch_bounds__(512) void scan_bsum_kernel(int* __restrict__ bsum, int nb) {
  __shared__ int s[512];
  int t = threadIdx.x;
  int v = (t < nb) ? bsum[t] : 0;
  s[t] = v;
  __syncthreads();
  for (int d = 1; d < 512; d <<= 1) {
    int xv = (t >= d) ? s[t - d] : 0;
    __syncthreads();
    s[t] += xv;
    __syncthreads();
  }
  if (t < nb) bsum[t] = s[t] - v;  // exclusive
}

__global__ __launch_bounds__(256) void scan_apply_kernel(const int* __restrict__ cnt,
                                                         const int* __restrict__ bsum,
                                                         int* __restrict__ rowptr,
                                                         int* __restrict__ cursor,
                                                         int N, int E) {
  __shared__ int s[256];
  int t = threadIdx.x;
  int i = blockIdx.x * 256 + t;
  int v = (i < N) ? cnt[i] : 0;
  s[t] = v;
  __syncthreads();
  for (int d = 1; d < 256; d <<= 1) {
    int xv = (t >= d) ? s[t - d] : 0;
    __syncthreads();
    s[t] += xv;
    __syncthreads();
  }
  int excl = s[t] - v + bsum[blockIdx.x];
  if (i < N) {
    rowptr[i] = excl;
    cursor[i] = excl;
  }
  if (i == N - 1) rowptr[N] = E;
}

__global__ __launch_bounds__(256) void scatter_kernel(const int* __restrict__ ei, int E,
                                                      const int* __restrict__ flag,
                                                      int* __restrict__ cursor,
                                                      int* __restrict__ csr_col) {
  int e = blockIdx.x * 256 + threadIdx.x;
  if (e < E) {
    int is64 = *flag;
    int d = edge_dst(ei, e, E, is64);
    int sv = edge_src(ei, e, is64);
    int pos = atomicAdd(&cursor[d], 1);
    csr_col[pos] = sv;
  }
}

// ---------------- casts ----------------
// x (fp32 [N][128]) -> xb (bf16), pad rows [N, Npad) zeroed
__global__ __launch_bounds__(256) void cast_x_kernel(const float* __restrict__ x,
                                                     unsigned int* __restrict__ xb32,
                                                     long long n_elems, long long n_valid) {
  long long base = ((long long)blockIdx.x * 256 + threadIdx.x) * 8;
  if (base >= n_elems) return;
  uint4 o;
  if (base < n_valid) {
    float4 v0 = *(const float4*)(x + base);
    float4 v1 = *(const float4*)(x + base + 4);
    o.x = (unsigned)f2bf(v0.x) | ((unsigned)f2bf(v0.y) << 16);
    o.y = (unsigned)f2bf(v0.z) | ((unsigned)f2bf(v0.w) << 16);
    o.z = (unsigned)f2bf(v1.x) | ((unsigned)f2bf(v1.y) << 16);
    o.w = (unsigned)f2bf(v1.z) | ((unsigned)f2bf(v1.w) << 16);
  } else {
    o = uint4{0, 0, 0, 0};
  }
  *(uint4*)(xb32 + (base >> 1)) = o;
}

// W1t[n][k] = bf16( k<128 ? W1l[k][n] : W1r[k-128][n] ), n<256, k<256
__global__ __launch_bounds__(256) void cast_w1_kernel(const float* __restrict__ W1l,
                                                      const float* __restrict__ W1r,
                                                      unsigned short* __restrict__ W1t) {
  int idx = blockIdx.x * 256 + threadIdx.x;
  if (idx >= 256 * 256) return;
  int n = idx >> 8, k = idx & 255;
  float v = (k < 128) ? W1l[(size_t)k * HID + n] : W1r[(size_t)(k - 128) * HID + n];
  W1t[(size_t)n * 256 + k] = f2bf(v);
}

// W2t[n][k] = bf16( n<40 ? W2l[k][n] : W2r[k][n-40] ), n<80, k<256
__global__ __launch_bounds__(256) void cast_w2_kernel(const float* __restrict__ W2l,
                                                      const float* __restrict__ W2r,
                                                      unsigned short* __restrict__ W2t) {
  int idx = blockIdx.x * 256 + threadIdx.x;
  if (idx >= 80 * 256) return;
  int n = idx >> 8, k = idx & 255;
  float v = (n < CLS) ? W2l[(size_t)k * CLS + n] : W2r[(size_t)k * CLS + (n - CLS)];
  W2t[(size_t)n * 256 + k] = f2bf(v);
}

// ---------------- layer-1 mean aggregation (bf16 in/out, fp32 accum) -------
__global__ __launch_bounds__(256) void agg1_kernel(const unsigned int* __restrict__ xb32,
                                                   const int* __restrict__ rowptr,
                                                   const int* __restrict__ col,
                                                   unsigned int* __restrict__ aggb32,
                                                   int N) {
  int wave = threadIdx.x >> 6, lane = threadIdx.x & 63;
  int row = blockIdx.x * 4 + wave;
  if (row >= N) return;
  int s0 = rowptr[row], s1 = rowptr[row + 1];
  float ax = 0.f, ay = 0.f;
  int j = s0;
  for (; j + 1 < s1; j += 2) {
    int c0 = col[j], c1 = col[j + 1];
    unsigned int u0 = xb32[(size_t)c0 * 64 + lane];
    unsigned int u1 = xb32[(size_t)c1 * 64 + lane];
    ax += bf2f((unsigned short)u0) + bf2f((unsigned short)u1);
    ay += bf2f((unsigned short)(u0 >> 16)) + bf2f((unsigned short)(u1 >> 16));
  }
  if (j < s1) {
    unsigned int u0 = xb32[(size_t)col[j] * 64 + lane];
    ax += bf2f((unsigned short)u0);
    ay += bf2f((unsigned short)(u0 >> 16));
  }
  float inv = 1.f / fmaxf((float)(s1 - s0), 1.f);
  aggb32[(size_t)row * 64 + lane] =
      (unsigned)f2bf(ax * inv) | ((unsigned)f2bf(ay * inv) << 16);
}

// ---------------- GEMM1 (MFMA): hb = relu([aggb|xb] @ W1t^T + b1) ----------
// BM=128, BN=128 (grid.y=2), BK=32, 4 waves (2x2), each wave 64x64 = 4x4 frags.
// LDS linear [row][k] with 64B rows -> frag ds_read_b128 = 2 lanes/bank (free).
__global__ __launch_bounds__(256) void gemm1_mfma(const unsigned short* __restrict__ aggb,
                                                  const unsigned short* __restrict__ xb,
                                                  const unsigned short* __restrict__ W1t,
                                                  const float* __restrict__ b1,
                                                  unsigned short* __restrict__ hb, int M) {
  __shared__ unsigned short Alds[128 * 32];
  __shared__ unsigned short Blds[128 * 32];
  int t = threadIdx.x, lane = t & 63, w = t >> 6;
  int wm = w >> 1, wn = w & 1;
  int m0 = blockIdx.x * 128, n0 = blockIdx.y * 128;
  f32x4 acc[4][4] = {};

  for (int k0 = 0; k0 < 256; k0 += 32) {
    const unsigned short* Asrc = (k0 < 128) ? aggb : xb;
    int keff = k0 & 127;
    __syncthreads();  // previous iter's frag reads complete
#pragma unroll
    for (int j = 0; j < 2; ++j) {  // A: granule g = row*4+kb, 16B each
      int g = (w * 2 + j) * 64 + lane;
      int row = g >> 2, kb = g & 3;
      const char* gp = (const char*)Asrc + ((size_t)(m0 + row) * 128 + keff) * 2 + kb * 16;
      __builtin_amdgcn_global_load_lds(GLB_AS(gp),
                                       LDS_AS((char*)Alds + (w * 2 + j) * 1024), 16, 0, 0);
    }
#pragma unroll
    for (int j = 0; j < 2; ++j) {  // B (pre-transposed W1t[n][k])
      int g = (w * 2 + j) * 64 + lane;
      int n = g >> 2, kb = g & 3;
      const char* gp = (const char*)W1t + ((size_t)(n0 + n) * 256 + k0) * 2 + kb * 16;
      __builtin_amdgcn_global_load_lds(GLB_AS(gp),
                                       LDS_AS((char*)Blds + (w * 2 + j) * 1024), 16, 0, 0);
    }
    __syncthreads();  // drains vmcnt (global_load_lds) + lgkm

    int lr = lane & 15, kb = lane >> 4;
    short8v a[4], b[4];
#pragma unroll
    for (int m = 0; m < 4; ++m)
      a[m] = *(const short8v*)((const char*)Alds + ((wm * 64 + m * 16 + lr) * 64 + kb * 16));
#pragma unroll
    for (int n = 0; n < 4; ++n)
      b[n] = *(const short8v*)((const char*)Blds + ((wn * 64 + n * 16 + lr) * 64 + kb * 16));
#pragma unroll
    for (int m = 0; m < 4; ++m)
#pragma unroll
      for (int n = 0; n < 4; ++n)
        acc[m][n] = __builtin_amdgcn_mfma_f32_16x16x32_bf16(a[m], b[n], acc[m][n], 0, 0, 0);
  }

  int lr = lane & 15, lq = lane >> 4;
#pragma unroll
  for (int n = 0; n < 4; ++n) {
    int col = n0 + wn * 64 + n * 16 + lr;
    float bias = b1[col];
#pragma unroll
    for (int m = 0; m < 4; ++m) {
#pragma unroll
      for (int r = 0; r < 4; ++r) {
        int rowg = m0 + wm * 64 + m * 16 + lq * 4 + r;
        if (rowg < M)
          hb[(size_t)rowg * 256 + col] = f2bf(fmaxf(acc[m][n][r] + bias, 0.f));
      }
    }
  }
}

// ---------------- GEMM2 (MFMA): pr = hb @ W2t^T  (M x 256 x 80, fp32 out) ---
// BM=128, BN=80 (5x16), BK=32, 4 waves: wave w owns rows [w*32, w*32+32).
__global__ __launch_bounds__(256) void gemm2_mfma(const unsigned short* __restrict__ hb,
                                                  const unsigned short* __restrict__ W2t,
                                                  float* __restrict__ pr, int M) {
  __shared__ unsigned short Alds[128 * 32];
  __shared__ unsigned short Blds[80 * 32];
  int t = threadIdx.x, lane = t & 63, w = t >> 6;
  int m0 = blockIdx.x * 128;
  f32x4 acc[2][5] = {};

  for (int k0 = 0; k0 < 256; k0 += 32) {
    __syncthreads();
#pragma unroll
    for (int j = 0; j < 2; ++j) {
      int g = (w * 2 + j) * 64 + lane;
      int row = g >> 2, kb = g & 3;
      const char* gp = (const char*)hb + ((size_t)(m0 + row) * 256 + k0) * 2 + kb * 16;
      __builtin_amdgcn_global_load_lds(GLB_AS(gp),
                                       LDS_AS((char*)Alds + (w * 2 + j) * 1024), 16, 0, 0);
    }
    // B: 80 rows * 4 granules = 320 granules = 5 issues; wave0 takes issues 0,4
    int nissue = (w == 0) ? 2 : 1;
    for (int jj = 0; jj < nissue; ++jj) {
      int issue = (jj == 0) ? w : 4;
      int g = issue * 64 + lane;
      int n = g >> 2, kb = g & 3;
      const char* gp = (const char*)W2t + ((size_t)n * 256 + k0) * 2 + kb * 16;
      __builtin_amdgcn_global_load_lds(GLB_AS(gp),
                                       LDS_AS((char*)Blds + issue * 1024), 16, 0, 0);
    }
    __syncthreads();

    int lr = lane & 15, kb = lane >> 4;
    short8v a[2], b[5];
#pragma unroll
    for (int m = 0; m < 2; ++m)
      a[m] = *(const short8v*)((const char*)Alds + ((w * 32 + m * 16 + lr) * 64 + kb * 16));
#pragma unroll
    for (int n = 0; n < 5; ++n)
      b[n] = *(const short8v*)((const char*)Blds + ((n * 16 + lr) * 64 + kb * 16));
#pragma unroll
    for (int m = 0; m < 2; ++m)
#pragma unroll
      for (int n = 0; n < 5; ++n)
        acc[m][n] = __builtin_amdgcn_mfma_f32_16x16x32_bf16(a[m], b[n], acc[m][n], 0, 0, 0);
  }

  int lr = lane & 15, lq = lane >> 4;
#pragma unroll
  for (int m = 0; m < 2; ++m) {
#pragma unroll
    for (int r = 0; r < 4; ++r) {
      int rowg = m0 + w * 32 + m * 16 + lq * 4 + r;
      if (rowg < M) {
#pragma unroll
        for (int n = 0; n < 5; ++n)
          pr[(size_t)rowg * 80 + n * 16 + lr] = acc[m][n][r];
      }
    }
  }
}

// ---------------- final: mean-aggregate p, add r + b2, log_softmax ---------
__global__ __launch_bounds__(256) void final_kernel(const int* __restrict__ rowptr,
                                                    const int* __restrict__ col,
                                                    const float* __restrict__ pr,
                                                    const float* __restrict__ b2,
                                                    float* __restrict__ out, int N) {
  int wave = threadIdx.x >> 6, lane = threadIdx.x & 63;
  int row = blockIdx.x * 4 + wave;
  if (row >= N) return;
  int s0 = rowptr[row], s1 = rowptr[row + 1];
  bool active = lane < CLS;
  float acc = 0.f;
  for (int j = s0; j < s1; ++j) {
    int c = col[j];
    if (active) acc += pr[(size_t)c * 80 + lane];
  }
  float inv = 1.f / fmaxf((float)(s1 - s0), 1.f);
  float v = active ? (acc * inv + pr[(size_t)row * 80 + CLS + lane] + b2[lane])
                   : -1e30f;
  float mx = v;
#pragma unroll
  for (int d = 32; d >= 1; d >>= 1) mx = fmaxf(mx, __shfl_xor(mx, d, 64));
  float ex = active ? expf(v - mx) : 0.f;
  float sum = ex;
#pragma unroll
  for (int d = 32; d >= 1; d >>= 1) sum += __shfl_xor(sum, d, 64);
  if (active) out[(size_t)row * CLS + lane] = v - mx - logf(sum);
}

// ---------------- host launcher ----------------
extern "C" void kernel_launch(void* const* d_in, const int* in_sizes, int n_in,
                              void* d_out, int out_size, void* d_ws, size_t ws_size,
                              hipStream_t stream) {
  (void)n_in; (void)out_size; (void)ws_size;
  const float* x   = (const float*)d_in[0];
  const int*   ei  = (const int*)d_in[1];
  const float* W1l = (const float*)d_in[2];
  const float* W1r = (const float*)d_in[3];
  const float* b1  = (const float*)d_in[4];
  const float* W2l = (const float*)d_in[5];
  const float* W2r = (const float*)d_in[6];
  const float* b2  = (const float*)d_in[7];
  float* out = (float*)d_out;

  const int N = in_sizes[0] / F_IN;
  const int E = in_sizes[1] / 2;
  const int Npad = (N + 127) & ~127;

  char* ws = (char*)d_ws;
  size_t off = 0;
  auto alloc = [&](size_t bytes) -> void* {
    void* p = ws + off;
    off = (off + bytes + 255) & ~(size_t)255;
    return p;
  };
  int* flag    = (int*)alloc(4);
  int* cnt     = (int*)alloc((size_t)N * 4);
  int* bsum    = (int*)alloc(4096);
  int* rowptr  = (int*)alloc(((size_t)N + 1) * 4);
  int* cursor  = (int*)alloc((size_t)N * 4);
  int* csr_col = (int*)alloc((size_t)E * 4);
  unsigned short* xb   = (unsigned short*)alloc((size_t)Npad * F_IN * 2);
  unsigned short* aggb = (unsigned short*)alloc((size_t)Npad * F_IN * 2);
  unsigned short* W1t  = (unsigned short*)alloc((size_t)256 * 256 * 2);
  unsigned short* W2t  = (unsigned short*)alloc((size_t)80 * 256 * 2);
  unsigned short* hb   = (unsigned short*)alloc((size_t)Npad * HID * 2);
  float* pr            = (float*)alloc((size_t)N * 80 * 4);

  hipMemsetAsync(cnt, 0, (size_t)N * 4, stream);
  detect_kernel<<<1, 64, 0, stream>>>(ei, flag);

  int eb = (E + 255) / 256;
  int nb = (N + 255) / 256;  // 391 <= 512 required by scan_bsum_kernel
  hist_kernel<<<eb, 256, 0, stream>>>(ei, E, flag, cnt);
  blocksum_kernel<<<nb, 256, 0, stream>>>(cnt, bsum, N);
  scan_bsum_kernel<<<1, 512, 0, stream>>>(bsum, nb);
  scan_apply_kernel<<<nb, 256, 0, stream>>>(cnt, bsum, rowptr, cursor, N, E);
  scatter_kernel<<<eb, 256, 0, stream>>>(ei, E, flag, cursor, csr_col);

  long long n_elems = (long long)Npad * F_IN, n_valid = (long long)N * F_IN;
  cast_x_kernel<<<(int)((n_elems / 8 + 255) / 256), 256, 0, stream>>>(
      x, (unsigned int*)xb, n_elems, n_valid);
  cast_w1_kernel<<<(256 * 256 + 255) / 256, 256, 0, stream>>>(W1l, W1r, W1t);
  cast_w2_kernel<<<(80 * 256 + 255) / 256, 256, 0, stream>>>(W2l, W2r, W2t);

  agg1_kernel<<<(N + 3) / 4, 256, 0, stream>>>((const unsigned int*)xb, rowptr, csr_col,
                                               (unsigned int*)aggb, N);

  dim3 g1(Npad / 128, 2);
  gemm1_mfma<<<g1, 256, 0, stream>>>(aggb, xb, W1t, b1, hb, N);
  gemm2_mfma<<<Npad / 128, 256, 0, stream>>>(hb, W2t, pr, N);
  final_kernel<<<(N + 3) / 4, 256, 0, stream>>>(rowptr, csr_col, pr, b2, out, N);
}

// Round 3
// 441.437 us; speedup vs baseline: 1.9170x; 1.2181x over previous
//
#include <hip/hip_runtime.h>
#include <math.h>

#define F_IN 128
#define HID  256
#define CLS  40

typedef __attribute__((ext_vector_type(8))) short short8v;   // 8 bf16 (4 VGPRs)
typedef __attribute__((ext_vector_type(4))) float f32x4;

#define GLB_AS(p) ((const __attribute__((address_space(1))) unsigned int*)(p))
#define LDS_AS(p) ((__attribute__((address_space(3))) unsigned int*)(p))

__device__ __forceinline__ float bf2f(unsigned short u) {
  unsigned int v = ((unsigned int)u) << 16;
  return __builtin_bit_cast(float, v);
}
__device__ __forceinline__ unsigned short f2bf(float f) {  // round-to-nearest-even
  unsigned int u = __builtin_bit_cast(unsigned int, f);
  u += 0x7fffu + ((u >> 16) & 1u);
  return (unsigned short)(u >> 16);
}

// ---------------- edge_index decode (int32 vs int64 hedge) ----------------
__global__ void detect_kernel(const int* __restrict__ ei, int* __restrict__ flag) {
  if (threadIdx.x == 0 && blockIdx.x == 0) {
    int ornz = 0;
    for (int i = 1; i < 256; i += 2) ornz |= ei[i];
    *flag = (ornz == 0) ? 1 : 0;
  }
}
__device__ __forceinline__ int edge_dst(const int* ei, int e, int E, int is64) {
  return is64 ? ei[2ll * E + 2ll * e] : ei[(long long)E + e];
}
__device__ __forceinline__ int edge_src(const int* ei, int e, int is64) {
  return is64 ? ei[2ll * e] : ei[e];
}

// ---------------- CSR build ----------------
__global__ __launch_bounds__(256) void hist_kernel(const int* __restrict__ ei, int E,
                                                   const int* __restrict__ flag,
                                                   int* __restrict__ cnt) {
  int e = blockIdx.x * 256 + threadIdx.x;
  if (e < E) {
    int is64 = *flag;
    atomicAdd(&cnt[edge_dst(ei, e, E, is64)], 1);
  }
}

__global__ __launch_bounds__(256) void blocksum_kernel(const int* __restrict__ cnt,
                                                       int* __restrict__ bsum, int n) {
  __shared__ int s[256];
  int t = threadIdx.x;
  int i = blockIdx.x * 256 + t;
  s[t] = (i < n) ? cnt[i] : 0;
  __syncthreads();
  for (int d = 128; d > 0; d >>= 1) {
    if (t < d) s[t] += s[t + d];
    __syncthreads();
  }
  if (t == 0) bsum[blockIdx.x] = s[0];
}

__global__ __launch_bounds__(512) void scan_bsum_kernel(int* __restrict__ bsum, int nb) {
  __shared__ int s[512];
  int t = threadIdx.x;
  int v = (t < nb) ? bsum[t] : 0;
  s[t] = v;
  __syncthreads();
  for (int d = 1; d < 512; d <<= 1) {
    int xv = (t >= d) ? s[t - d] : 0;
    __syncthreads();
    s[t] += xv;
    __syncthreads();
  }
  if (t < nb) bsum[t] = s[t] - v;  // exclusive
}

__global__ __launch_bounds__(256) void scan_apply_kernel(const int* __restrict__ cnt,
                                                         const int* __restrict__ bsum,
                                                         int* __restrict__ rowptr,
                                                         int* __restrict__ cursor,
                                                         int N, int E) {
  __shared__ int s[256];
  int t = threadIdx.x;
  int i = blockIdx.x * 256 + t;
  int v = (i < N) ? cnt[i] : 0;
  s[t] = v;
  __syncthreads();
  for (int d = 1; d < 256; d <<= 1) {
    int xv = (t >= d) ? s[t - d] : 0;
    __syncthreads();
    s[t] += xv;
    __syncthreads();
  }
  int excl = s[t] - v + bsum[blockIdx.x];
  if (i < N) {
    rowptr[i] = excl;
    cursor[i] = excl;
  }
  if (i == N - 1) rowptr[N] = E;
}

__global__ __launch_bounds__(256) void scatter_kernel(const int* __restrict__ ei, int E,
                                                      const int* __restrict__ flag,
                                                      int* __restrict__ cursor,
                                                      int* __restrict__ csr_col) {
  int e = blockIdx.x * 256 + threadIdx.x;
  if (e < E) {
    int is64 = *flag;
    int d = edge_dst(ei, e, E, is64);
    int sv = edge_src(ei, e, is64);
    int pos = atomicAdd(&cursor[d], 1);
    csr_col[pos] = sv;
  }
}

// ---------------- casts ----------------
__global__ __launch_bounds__(256) void cast_x_kernel(const float* __restrict__ x,
                                                     unsigned int* __restrict__ xb32,
                                                     long long n_elems, long long n_valid) {
  long long base = ((long long)blockIdx.x * 256 + threadIdx.x) * 8;
  if (base >= n_elems) return;
  uint4 o;
  if (base < n_valid) {
    float4 v0 = *(const float4*)(x + base);
    float4 v1 = *(const float4*)(x + base + 4);
    o.x = (unsigned)f2bf(v0.x) | ((unsigned)f2bf(v0.y) << 16);
    o.y = (unsigned)f2bf(v0.z) | ((unsigned)f2bf(v0.w) << 16);
    o.z = (unsigned)f2bf(v1.x) | ((unsigned)f2bf(v1.y) << 16);
    o.w = (unsigned)f2bf(v1.z) | ((unsigned)f2bf(v1.w) << 16);
  } else {
    o = uint4{0, 0, 0, 0};
  }
  *(uint4*)(xb32 + (base >> 1)) = o;
}

// W1t[n][k] = bf16( k<128 ? W1l[k][n] : W1r[k-128][n] ), n<256, k<256
__global__ __launch_bounds__(256) void cast_w1_kernel(const float* __restrict__ W1l,
                                                      const float* __restrict__ W1r,
                                                      unsigned short* __restrict__ W1t) {
  int idx = blockIdx.x * 256 + threadIdx.x;
  if (idx >= 256 * 256) return;
  int n = idx >> 8, k = idx & 255;
  float v = (k < 128) ? W1l[(size_t)k * HID + n] : W1r[(size_t)(k - 128) * HID + n];
  W1t[(size_t)n * 256 + k] = f2bf(v);
}

// W2t[n][k] = bf16( n<40 ? W2l[k][n] : W2r[k][n-40] ), n<80, k<256
__global__ __launch_bounds__(256) void cast_w2_kernel(const float* __restrict__ W2l,
                                                      const float* __restrict__ W2r,
                                                      unsigned short* __restrict__ W2t) {
  int idx = blockIdx.x * 256 + threadIdx.x;
  if (idx >= 80 * 256) return;
  int n = idx >> 8, k = idx & 255;
  float v = (n < CLS) ? W2l[(size_t)k * CLS + n] : W2r[(size_t)k * CLS + (n - CLS)];
  W2t[(size_t)n * 256 + k] = f2bf(v);
}

// ---------------- layer-1 mean aggregation (bf16, fp32 accum, x4 unroll) ---
__global__ __launch_bounds__(256) void agg1_kernel(const unsigned int* __restrict__ xb32,
                                                   const int* __restrict__ rowptr,
                                                   const int* __restrict__ col,
                                                   unsigned int* __restrict__ aggb32,
                                                   int N) {
  int wave = threadIdx.x >> 6, lane = threadIdx.x & 63;
  int row = blockIdx.x * 4 + wave;
  if (row >= N) return;
  int s0 = rowptr[row], s1 = rowptr[row + 1];
  float ax = 0.f, ay = 0.f;
  int j = s0;
  for (; j + 3 < s1; j += 4) {  // 4 independent gathers in flight
    int c0 = col[j], c1 = col[j + 1], c2 = col[j + 2], c3 = col[j + 3];
    unsigned int u0 = xb32[(size_t)c0 * 64 + lane];
    unsigned int u1 = xb32[(size_t)c1 * 64 + lane];
    unsigned int u2 = xb32[(size_t)c2 * 64 + lane];
    unsigned int u3 = xb32[(size_t)c3 * 64 + lane];
    ax += (bf2f((unsigned short)u0) + bf2f((unsigned short)u1)) +
          (bf2f((unsigned short)u2) + bf2f((unsigned short)u3));
    ay += (bf2f((unsigned short)(u0 >> 16)) + bf2f((unsigned short)(u1 >> 16))) +
          (bf2f((unsigned short)(u2 >> 16)) + bf2f((unsigned short)(u3 >> 16)));
  }
  for (; j < s1; ++j) {
    unsigned int u0 = xb32[(size_t)col[j] * 64 + lane];
    ax += bf2f((unsigned short)u0);
    ay += bf2f((unsigned short)(u0 >> 16));
  }
  float inv = 1.f / fmaxf((float)(s1 - s0), 1.f);
  aggb32[(size_t)row * 64 + lane] =
      (unsigned)f2bf(ax * inv) | ((unsigned)f2bf(ay * inv) << 16);
}

// ---------------- GEMM1 (MFMA): hb = relu([aggb|xb] @ W1t^T + b1) ----------
__global__ __launch_bounds__(256) void gemm1_mfma(const unsigned short* __restrict__ aggb,
                                                  const unsigned short* __restrict__ xb,
                                                  const unsigned short* __restrict__ W1t,
                                                  const float* __restrict__ b1,
                                                  unsigned short* __restrict__ hb, int M) {
  __shared__ unsigned short Alds[128 * 32];
  __shared__ unsigned short Blds[128 * 32];
  int t = threadIdx.x, lane = t & 63, w = t >> 6;
  int wm = w >> 1, wn = w & 1;
  int m0 = blockIdx.x * 128, n0 = blockIdx.y * 128;
  f32x4 acc[4][4] = {};

  for (int k0 = 0; k0 < 256; k0 += 32) {
    const unsigned short* Asrc = (k0 < 128) ? aggb : xb;
    int keff = k0 & 127;
    __syncthreads();
#pragma unroll
    for (int j = 0; j < 2; ++j) {
      int g = (w * 2 + j) * 64 + lane;
      int row = g >> 2, kb = g & 3;
      const char* gp = (const char*)Asrc + ((size_t)(m0 + row) * 128 + keff) * 2 + kb * 16;
      __builtin_amdgcn_global_load_lds(GLB_AS(gp),
                                       LDS_AS((char*)Alds + (w * 2 + j) * 1024), 16, 0, 0);
    }
#pragma unroll
    for (int j = 0; j < 2; ++j) {
      int g = (w * 2 + j) * 64 + lane;
      int n = g >> 2, kb = g & 3;
      const char* gp = (const char*)W1t + ((size_t)(n0 + n) * 256 + k0) * 2 + kb * 16;
      __builtin_amdgcn_global_load_lds(GLB_AS(gp),
                                       LDS_AS((char*)Blds + (w * 2 + j) * 1024), 16, 0, 0);
    }
    __syncthreads();

    int lr = lane & 15, kb = lane >> 4;
    short8v a[4], b[4];
#pragma unroll
    for (int m = 0; m < 4; ++m)
      a[m] = *(const short8v*)((const char*)Alds + ((wm * 64 + m * 16 + lr) * 64 + kb * 16));
#pragma unroll
    for (int n = 0; n < 4; ++n)
      b[n] = *(const short8v*)((const char*)Blds + ((wn * 64 + n * 16 + lr) * 64 + kb * 16));
#pragma unroll
    for (int m = 0; m < 4; ++m)
#pragma unroll
      for (int n = 0; n < 4; ++n)
        acc[m][n] = __builtin_amdgcn_mfma_f32_16x16x32_bf16(a[m], b[n], acc[m][n], 0, 0, 0);
  }

  int lr = lane & 15, lq = lane >> 4;
#pragma unroll
  for (int n = 0; n < 4; ++n) {
    int col = n0 + wn * 64 + n * 16 + lr;
    float bias = b1[col];
#pragma unroll
    for (int m = 0; m < 4; ++m) {
#pragma unroll
      for (int r = 0; r < 4; ++r) {
        int rowg = m0 + wm * 64 + m * 16 + lq * 4 + r;
        if (rowg < M)
          hb[(size_t)rowg * 256 + col] = f2bf(fmaxf(acc[m][n][r] + bias, 0.f));
      }
    }
  }
}

// ---------------- GEMM2 (MFMA): [p|r] = hb @ W2t^T ------------------------
// p (cols 0..39)  -> ppb bf16-packed [N][20] uints (gathered by final)
// r (cols 40..79) -> rr fp32 [N][40] with b2 folded in (streamed by final)
__global__ __launch_bounds__(256) void gemm2_mfma(const unsigned short* __restrict__ hb,
                                                  const unsigned short* __restrict__ W2t,
                                                  const float* __restrict__ b2,
                                                  unsigned short* __restrict__ pp,
                                                  float* __restrict__ rr, int M) {
  __shared__ unsigned short Alds[128 * 32];
  __shared__ unsigned short Blds[80 * 32];
  int t = threadIdx.x, lane = t & 63, w = t >> 6;
  int m0 = blockIdx.x * 128;
  f32x4 acc[2][5] = {};

  for (int k0 = 0; k0 < 256; k0 += 32) {
    __syncthreads();
#pragma unroll
    for (int j = 0; j < 2; ++j) {
      int g = (w * 2 + j) * 64 + lane;
      int row = g >> 2, kb = g & 3;
      const char* gp = (const char*)hb + ((size_t)(m0 + row) * 256 + k0) * 2 + kb * 16;
      __builtin_amdgcn_global_load_lds(GLB_AS(gp),
                                       LDS_AS((char*)Alds + (w * 2 + j) * 1024), 16, 0, 0);
    }
    int nissue = (w == 0) ? 2 : 1;
    for (int jj = 0; jj < nissue; ++jj) {
      int issue = (jj == 0) ? w : 4;
      int g = issue * 64 + lane;
      int n = g >> 2, kb = g & 3;
      const char* gp = (const char*)W2t + ((size_t)n * 256 + k0) * 2 + kb * 16;
      __builtin_amdgcn_global_load_lds(GLB_AS(gp),
                                       LDS_AS((char*)Blds + issue * 1024), 16, 0, 0);
    }
    __syncthreads();

    int lr = lane & 15, kb = lane >> 4;
    short8v a[2], b[5];
#pragma unroll
    for (int m = 0; m < 2; ++m)
      a[m] = *(const short8v*)((const char*)Alds + ((w * 32 + m * 16 + lr) * 64 + kb * 16));
#pragma unroll
    for (int n = 0; n < 5; ++n)
      b[n] = *(const short8v*)((const char*)Blds + ((n * 16 + lr) * 64 + kb * 16));
#pragma unroll
    for (int m = 0; m < 2; ++m)
#pragma unroll
      for (int n = 0; n < 5; ++n)
        acc[m][n] = __builtin_amdgcn_mfma_f32_16x16x32_bf16(a[m], b[n], acc[m][n], 0, 0, 0);
  }

  int lr = lane & 15, lq = lane >> 4;
#pragma unroll
  for (int m = 0; m < 2; ++m) {
#pragma unroll
    for (int r = 0; r < 4; ++r) {
      int rowg = m0 + w * 32 + m * 16 + lq * 4 + r;
      if (rowg < M) {
#pragma unroll
        for (int n = 0; n < 5; ++n) {
          int c = n * 16 + lr;
          float v = acc[m][n][r];
          if (c < CLS)
            pp[(size_t)rowg * CLS + c] = f2bf(v);
          else
            rr[(size_t)rowg * CLS + (c - CLS)] = v + b2[c - CLS];
        }
      }
    }
  }
}

// ---------------- final: mean-aggregate bf16 p, add rr, log_softmax -------
// lanes 0..19 active for gather; lane l owns classes 2l, 2l+1.
__global__ __launch_bounds__(256) void final_kernel(const int* __restrict__ rowptr,
                                                    const int* __restrict__ col,
                                                    const unsigned int* __restrict__ pp32,
                                                    const float* __restrict__ rr,
                                                    float* __restrict__ out, int N) {
  int wave = threadIdx.x >> 6, lane = threadIdx.x & 63;
  int row = blockIdx.x * 4 + wave;
  if (row >= N) return;
  int s0 = rowptr[row], s1 = rowptr[row + 1];
  bool active = lane < 20;
  float a0 = 0.f, a1 = 0.f;
  int j = s0;
  for (; j + 3 < s1; j += 4) {  // 4 independent gathers in flight
    int c0 = col[j], c1 = col[j + 1], c2 = col[j + 2], c3 = col[j + 3];
    if (active) {
      unsigned int u0 = pp32[(size_t)c0 * 20 + lane];
      unsigned int u1 = pp32[(size_t)c1 * 20 + lane];
      unsigned int u2 = pp32[(size_t)c2 * 20 + lane];
      unsigned int u3 = pp32[(size_t)c3 * 20 + lane];
      a0 += (bf2f((unsigned short)u0) + bf2f((unsigned short)u1)) +
            (bf2f((unsigned short)u2) + bf2f((unsigned short)u3));
      a1 += (bf2f((unsigned short)(u0 >> 16)) + bf2f((unsigned short)(u1 >> 16))) +
            (bf2f((unsigned short)(u2 >> 16)) + bf2f((unsigned short)(u3 >> 16)));
    }
  }
  for (; j < s1; ++j) {
    int c = col[j];
    if (active) {
      unsigned int u = pp32[(size_t)c * 20 + lane];
      a0 += bf2f((unsigned short)u);
      a1 += bf2f((unsigned short)(u >> 16));
    }
  }
  float inv = 1.f / fmaxf((float)(s1 - s0), 1.f);
  float v0 = -1e30f, v1 = -1e30f;
  if (active) {
    float2 rv = *(const float2*)(rr + (size_t)row * CLS + lane * 2);
    v0 = a0 * inv + rv.x;
    v1 = a1 * inv + rv.y;
  }
  float mx = fmaxf(v0, v1);
#pragma unroll
  for (int d = 32; d >= 1; d >>= 1) mx = fmaxf(mx, __shfl_xor(mx, d, 64));
  float ex = active ? (expf(v0 - mx) + expf(v1 - mx)) : 0.f;
  float sum = ex;
#pragma unroll
  for (int d = 32; d >= 1; d >>= 1) sum += __shfl_xor(sum, d, 64);
  float ls = logf(sum);
  if (active) {
    float2 o;
    o.x = v0 - mx - ls;
    o.y = v1 - mx - ls;
    *(float2*)(out + (size_t)row * CLS + lane * 2) = o;
  }
}

// ---------------- host launcher ----------------
extern "C" void kernel_launch(void* const* d_in, const int* in_sizes, int n_in,
                              void* d_out, int out_size, void* d_ws, size_t ws_size,
                              hipStream_t stream) {
  (void)n_in; (void)out_size; (void)ws_size;
  const float* x   = (const float*)d_in[0];
  const int*   ei  = (const int*)d_in[1];
  const float* W1l = (const float*)d_in[2];
  const float* W1r = (const float*)d_in[3];
  const float* b1  = (const float*)d_in[4];
  const float* W2l = (const float*)d_in[5];
  const float* W2r = (const float*)d_in[6];
  const float* b2  = (const float*)d_in[7];
  float* out = (float*)d_out;

  const int N = in_sizes[0] / F_IN;
  const int E = in_sizes[1] / 2;
  const int Npad = (N + 127) & ~127;

  char* ws = (char*)d_ws;
  size_t off = 0;
  auto alloc = [&](size_t bytes) -> void* {
    void* p = ws + off;
    off = (off + bytes + 255) & ~(size_t)255;
    return p;
  };
  int* flag    = (int*)alloc(4);
  int* cnt     = (int*)alloc((size_t)N * 4);
  int* bsum    = (int*)alloc(4096);
  int* rowptr  = (int*)alloc(((size_t)N + 1) * 4);
  int* cursor  = (int*)alloc((size_t)N * 4);
  int* csr_col = (int*)alloc((size_t)E * 4);
  unsigned short* xb   = (unsigned short*)alloc((size_t)Npad * F_IN * 2);
  unsigned short* aggb = (unsigned short*)alloc((size_t)Npad * F_IN * 2);
  unsigned short* W1t  = (unsigned short*)alloc((size_t)256 * 256 * 2);
  unsigned short* W2t  = (unsigned short*)alloc((size_t)80 * 256 * 2);
  unsigned short* hb   = (unsigned short*)alloc((size_t)Npad * HID * 2);
  unsigned short* pp   = (unsigned short*)alloc((size_t)N * CLS * 2);
  float* rr            = (float*)alloc((size_t)N * CLS * 4);

  hipMemsetAsync(cnt, 0, (size_t)N * 4, stream);
  detect_kernel<<<1, 64, 0, stream>>>(ei, flag);

  int eb = (E + 255) / 256;
  int nb = (N + 255) / 256;  // 391 <= 512 required by scan_bsum_kernel
  hist_kernel<<<eb, 256, 0, stream>>>(ei, E, flag, cnt);
  blocksum_kernel<<<nb, 256, 0, stream>>>(cnt, bsum, N);
  scan_bsum_kernel<<<1, 512, 0, stream>>>(bsum, nb);
  scan_apply_kernel<<<nb, 256, 0, stream>>>(cnt, bsum, rowptr, cursor, N, E);
  scatter_kernel<<<eb, 256, 0, stream>>>(ei, E, flag, cursor, csr_col);

  long long n_elems = (long long)Npad * F_IN, n_valid = (long long)N * F_IN;
  cast_x_kernel<<<(int)((n_elems / 8 + 255) / 256), 256, 0, stream>>>(
      x, (unsigned int*)xb, n_elems, n_valid);
  cast_w1_kernel<<<(256 * 256 + 255) / 256, 256, 0, stream>>>(W1l, W1r, W1t);
  cast_w2_kernel<<<(80 * 256 + 255) / 256, 256, 0, stream>>>(W2l, W2r, W2t);

  agg1_kernel<<<(N + 3) / 4, 256, 0, stream>>>((const unsigned int*)xb, rowptr, csr_col,
                                               (unsigned int*)aggb, N);

  dim3 g1(Npad / 128, 2);
  gemm1_mfma<<<g1, 256, 0, stream>>>(aggb, xb, W1t, b1, hb, N);
  gemm2_mfma<<<Npad / 128, 256, 0, stream>>>(hb, W2t, b2, pp, rr, N);
  final_kernel<<<(N + 3) / 4, 256, 0, stream>>>(rowptr, csr_col, (const unsigned int*)pp,
                                                rr, out, N);
}

// Round 4
// 380.692 us; speedup vs baseline: 2.2229x; 1.1596x over previous
//
#include <hip/hip_runtime.h>
#include <math.h>

#define F_IN 128
#define HID  256
#define CLS  40
#define NPART 8

typedef __attribute__((ext_vector_type(8))) short short8v;   // 8 bf16 (4 VGPRs)
typedef __attribute__((ext_vector_type(4))) float f32x4;

#define GLB_AS(p) ((const __attribute__((address_space(1))) unsigned int*)(p))
#define LDS_AS(p) ((__attribute__((address_space(3))) unsigned int*)(p))

__device__ __forceinline__ float bf2f(unsigned short u) {
  unsigned int v = ((unsigned int)u) << 16;
  return __builtin_bit_cast(float, v);
}
__device__ __forceinline__ unsigned short f2bf(float f) {  // round-to-nearest-even
  unsigned int u = __builtin_bit_cast(unsigned int, f);
  u += 0x7fffu + ((u >> 16) & 1u);
  return (unsigned short)(u >> 16);
}

// ---------------- edge_index decode (int32 vs int64 hedge) ----------------
__global__ void detect_kernel(const int* __restrict__ ei, int* __restrict__ flag) {
  if (threadIdx.x == 0 && blockIdx.x == 0) {
    int ornz = 0;
    for (int i = 1; i < 256; i += 2) ornz |= ei[i];
    *flag = (ornz == 0) ? 1 : 0;
  }
}
__device__ __forceinline__ int edge_dst(const int* ei, int e, int E, int is64) {
  return is64 ? ei[2ll * E + 2ll * e] : ei[(long long)E + e];
}
__device__ __forceinline__ int edge_src(const int* ei, int e, int is64) {
  return is64 ? ei[2ll * e] : ei[e];
}

// ---------------- CSR build (DST-partitioned: partition = blockIdx & 7) ----
// Each partition group scans all edges, handles only its dst range. Writes
// (cnt / cursor / csr_col) stay XCD-local -> no cross-XCD line ping-pong.
__global__ __launch_bounds__(256) void hist_part_kernel(const int* __restrict__ ei, int E,
                                                        const int* __restrict__ flag,
                                                        int* __restrict__ cnt, int pstep,
                                                        int N) {
  int pid = blockIdx.x & (NPART - 1);
  int lo = pid * pstep;
  int hi = min(lo + pstep, N);
  int is64 = *flag;
  int nblk = gridDim.x >> 3;
  int bslot = blockIdx.x >> 3;
  int stride = nblk * 256 * 2;
  for (int e = (bslot * 256 + threadIdx.x) * 2; e < E; e += stride) {
    int d0 = edge_dst(ei, e, E, is64);
    int d1 = edge_dst(ei, e + 1, E, is64);
    if (d0 >= lo && d0 < hi) atomicAdd(&cnt[d0], 1);
    if (d1 >= lo && d1 < hi) atomicAdd(&cnt[d1], 1);
  }
}

__global__ __launch_bounds__(256) void scatter_part_kernel(const int* __restrict__ ei, int E,
                                                           const int* __restrict__ flag,
                                                           int* __restrict__ cursor,
                                                           int* __restrict__ csr_col,
                                                           int pstep, int N) {
  int pid = blockIdx.x & (NPART - 1);
  int lo = pid * pstep;
  int hi = min(lo + pstep, N);
  int is64 = *flag;
  int nblk = gridDim.x >> 3;
  int bslot = blockIdx.x >> 3;
  int stride = nblk * 256 * 2;
  for (int e = (bslot * 256 + threadIdx.x) * 2; e < E; e += stride) {
    int d0 = edge_dst(ei, e, E, is64);
    int d1 = edge_dst(ei, e + 1, E, is64);
    if (d0 >= lo && d0 < hi) {
      int sv = edge_src(ei, e, is64);
      int pos = atomicAdd(&cursor[d0], 1);
      csr_col[pos] = sv;
    }
    if (d1 >= lo && d1 < hi) {
      int sv = edge_src(ei, e + 1, is64);
      int pos = atomicAdd(&cursor[d1], 1);
      csr_col[pos] = sv;
    }
  }
}

__global__ __launch_bounds__(256) void blocksum_kernel(const int* __restrict__ cnt,
                                                       int* __restrict__ bsum, int n) {
  __shared__ int s[256];
  int t = threadIdx.x;
  int i = blockIdx.x * 256 + t;
  s[t] = (i < n) ? cnt[i] : 0;
  __syncthreads();
  for (int d = 128; d > 0; d >>= 1) {
    if (t < d) s[t] += s[t + d];
    __syncthreads();
  }
  if (t == 0) bsum[blockIdx.x] = s[0];
}

__global__ __launch_bounds__(512) void scan_bsum_kernel(int* __restrict__ bsum, int nb) {
  __shared__ int s[512];
  int t = threadIdx.x;
  int v = (t < nb) ? bsum[t] : 0;
  s[t] = v;
  __syncthreads();
  for (int d = 1; d < 512; d <<= 1) {
    int xv = (t >= d) ? s[t - d] : 0;
    __syncthreads();
    s[t] += xv;
    __syncthreads();
  }
  if (t < nb) bsum[t] = s[t] - v;  // exclusive
}

__global__ __launch_bounds__(256) void scan_apply_kernel(const int* __restrict__ cnt,
                                                         const int* __restrict__ bsum,
                                                         int* __restrict__ rowptr,
                                                         int* __restrict__ cursor,
                                                         int N, int E) {
  __shared__ int s[256];
  int t = threadIdx.x;
  int i = blockIdx.x * 256 + t;
  int v = (i < N) ? cnt[i] : 0;
  s[t] = v;
  __syncthreads();
  for (int d = 1; d < 256; d <<= 1) {
    int xv = (t >= d) ? s[t - d] : 0;
    __syncthreads();
    s[t] += xv;
    __syncthreads();
  }
  int excl = s[t] - v + bsum[blockIdx.x];
  if (i < N) {
    rowptr[i] = excl;
    cursor[i] = excl;
  }
  if (i == N - 1) rowptr[N] = E;
}

// ---------------- casts ----------------
__global__ __launch_bounds__(256) void cast_x_kernel(const float* __restrict__ x,
                                                     unsigned int* __restrict__ xb32,
                                                     long long n_elems, long long n_valid) {
  long long base = ((long long)blockIdx.x * 256 + threadIdx.x) * 8;
  if (base >= n_elems) return;
  uint4 o;
  if (base < n_valid) {
    float4 v0 = *(const float4*)(x + base);
    float4 v1 = *(const float4*)(x + base + 4);
    o.x = (unsigned)f2bf(v0.x) | ((unsigned)f2bf(v0.y) << 16);
    o.y = (unsigned)f2bf(v0.z) | ((unsigned)f2bf(v0.w) << 16);
    o.z = (unsigned)f2bf(v1.x) | ((unsigned)f2bf(v1.y) << 16);
    o.w = (unsigned)f2bf(v1.z) | ((unsigned)f2bf(v1.w) << 16);
  } else {
    o = uint4{0, 0, 0, 0};
  }
  *(uint4*)(xb32 + (base >> 1)) = o;
}

// W1t[n][k] = bf16( k<128 ? W1l[k][n] : W1r[k-128][n] ), n<256, k<256
__global__ __launch_bounds__(256) void cast_w1_kernel(const float* __restrict__ W1l,
                                                      const float* __restrict__ W1r,
                                                      unsigned short* __restrict__ W1t) {
  int idx = blockIdx.x * 256 + threadIdx.x;
  if (idx >= 256 * 256) return;
  int n = idx >> 8, k = idx & 255;
  float v = (k < 128) ? W1l[(size_t)k * HID + n] : W1r[(size_t)(k - 128) * HID + n];
  W1t[(size_t)n * 256 + k] = f2bf(v);
}

// W2t[n][k] = bf16( n<40 ? W2l[k][n] : W2r[k][n-40] ), n<80, k<256
__global__ __launch_bounds__(256) void cast_w2_kernel(const float* __restrict__ W2l,
                                                      const float* __restrict__ W2r,
                                                      unsigned short* __restrict__ W2t) {
  int idx = blockIdx.x * 256 + threadIdx.x;
  if (idx >= 80 * 256) return;
  int n = idx >> 8, k = idx & 255;
  float v = (n < CLS) ? W2l[(size_t)k * CLS + n] : W2r[(size_t)k * CLS + (n - CLS)];
  W2t[(size_t)n * 256 + k] = f2bf(v);
}

// ---------------- layer-1 mean aggregation (bf16, fp32 accum, x8 unroll) ---
__global__ __launch_bounds__(256) void agg1_kernel(const unsigned int* __restrict__ xb32,
                                                   const int* __restrict__ rowptr,
                                                   const int* __restrict__ col,
                                                   unsigned int* __restrict__ aggb32,
                                                   int N) {
  int wave = threadIdx.x >> 6, lane = threadIdx.x & 63;
  int row = blockIdx.x * 4 + wave;
  if (row >= N) return;
  int s0 = rowptr[row], s1 = rowptr[row + 1];
  float ax = 0.f, ay = 0.f;
  int j = s0;
  for (; j + 7 < s1; j += 8) {  // 8 independent gathers in flight
    unsigned int u[8];
#pragma unroll
    for (int q = 0; q < 8; ++q) u[q] = xb32[(size_t)col[j + q] * 64 + lane];
#pragma unroll
    for (int q = 0; q < 8; ++q) {
      ax += bf2f((unsigned short)u[q]);
      ay += bf2f((unsigned short)(u[q] >> 16));
    }
  }
  for (; j < s1; ++j) {
    unsigned int u0 = xb32[(size_t)col[j] * 64 + lane];
    ax += bf2f((unsigned short)u0);
    ay += bf2f((unsigned short)(u0 >> 16));
  }
  float inv = 1.f / fmaxf((float)(s1 - s0), 1.f);
  aggb32[(size_t)row * 64 + lane] =
      (unsigned)f2bf(ax * inv) | ((unsigned)f2bf(ay * inv) << 16);
}

// ---------------- GEMM1 (MFMA): hb = relu([aggb|xb] @ W1t^T + b1) ----------
__global__ __launch_bounds__(256) void gemm1_mfma(const unsigned short* __restrict__ aggb,
                                                  const unsigned short* __restrict__ xb,
                                                  const unsigned short* __restrict__ W1t,
                                                  const float* __restrict__ b1,
                                                  unsigned short* __restrict__ hb, int M) {
  __shared__ unsigned short Alds[128 * 32];
  __shared__ unsigned short Blds[128 * 32];
  int t = threadIdx.x, lane = t & 63, w = t >> 6;
  int wm = w >> 1, wn = w & 1;
  int m0 = blockIdx.x * 128, n0 = blockIdx.y * 128;
  f32x4 acc[4][4] = {};

  for (int k0 = 0; k0 < 256; k0 += 32) {
    const unsigned short* Asrc = (k0 < 128) ? aggb : xb;
    int keff = k0 & 127;
    __syncthreads();
#pragma unroll
    for (int j = 0; j < 2; ++j) {
      int g = (w * 2 + j) * 64 + lane;
      int row = g >> 2, kb = g & 3;
      const char* gp = (const char*)Asrc + ((size_t)(m0 + row) * 128 + keff) * 2 + kb * 16;
      __builtin_amdgcn_global_load_lds(GLB_AS(gp),
                                       LDS_AS((char*)Alds + (w * 2 + j) * 1024), 16, 0, 0);
    }
#pragma unroll
    for (int j = 0; j < 2; ++j) {
      int g = (w * 2 + j) * 64 + lane;
      int n = g >> 2, kb = g & 3;
      const char* gp = (const char*)W1t + ((size_t)(n0 + n) * 256 + k0) * 2 + kb * 16;
      __builtin_amdgcn_global_load_lds(GLB_AS(gp),
                                       LDS_AS((char*)Blds + (w * 2 + j) * 1024), 16, 0, 0);
    }
    __syncthreads();

    int lr = lane & 15, kb = lane >> 4;
    short8v a[4], b[4];
#pragma unroll
    for (int m = 0; m < 4; ++m)
      a[m] = *(const short8v*)((const char*)Alds + ((wm * 64 + m * 16 + lr) * 64 + kb * 16));
#pragma unroll
    for (int n = 0; n < 4; ++n)
      b[n] = *(const short8v*)((const char*)Blds + ((wn * 64 + n * 16 + lr) * 64 + kb * 16));
#pragma unroll
    for (int m = 0; m < 4; ++m)
#pragma unroll
      for (int n = 0; n < 4; ++n)
        acc[m][n] = __builtin_amdgcn_mfma_f32_16x16x32_bf16(a[m], b[n], acc[m][n], 0, 0, 0);
  }

  int lr = lane & 15, lq = lane >> 4;
#pragma unroll
  for (int n = 0; n < 4; ++n) {
    int col = n0 + wn * 64 + n * 16 + lr;
    float bias = b1[col];
#pragma unroll
    for (int m = 0; m < 4; ++m) {
#pragma unroll
      for (int r = 0; r < 4; ++r) {
        int rowg = m0 + wm * 64 + m * 16 + lq * 4 + r;
        if (rowg < M)
          hb[(size_t)rowg * 256 + col] = f2bf(fmaxf(acc[m][n][r] + bias, 0.f));
      }
    }
  }
}

// ---------------- GEMM2 (MFMA): [p|r] = hb @ W2t^T ------------------------
__global__ __launch_bounds__(256) void gemm2_mfma(const unsigned short* __restrict__ hb,
                                                  const unsigned short* __restrict__ W2t,
                                                  const float* __restrict__ b2,
                                                  unsigned short* __restrict__ pp,
                                                  float* __restrict__ rr, int M) {
  __shared__ unsigned short Alds[128 * 32];
  __shared__ unsigned short Blds[80 * 32];
  int t = threadIdx.x, lane = t & 63, w = t >> 6;
  int m0 = blockIdx.x * 128;
  f32x4 acc[2][5] = {};

  for (int k0 = 0; k0 < 256; k0 += 32) {
    __syncthreads();
#pragma unroll
    for (int j = 0; j < 2; ++j) {
      int g = (w * 2 + j) * 64 + lane;
      int row = g >> 2, kb = g & 3;
      const char* gp = (const char*)hb + ((size_t)(m0 + row) * 256 + k0) * 2 + kb * 16;
      __builtin_amdgcn_global_load_lds(GLB_AS(gp),
                                       LDS_AS((char*)Alds + (w * 2 + j) * 1024), 16, 0, 0);
    }
    int nissue = (w == 0) ? 2 : 1;
    for (int jj = 0; jj < nissue; ++jj) {
      int issue = (jj == 0) ? w : 4;
      int g = issue * 64 + lane;
      int n = g >> 2, kb = g & 3;
      const char* gp = (const char*)W2t + ((size_t)n * 256 + k0) * 2 + kb * 16;
      __builtin_amdgcn_global_load_lds(GLB_AS(gp),
                                       LDS_AS((char*)Blds + issue * 1024), 16, 0, 0);
    }
    __syncthreads();

    int lr = lane & 15, kb = lane >> 4;
    short8v a[2], b[5];
#pragma unroll
    for (int m = 0; m < 2; ++m)
      a[m] = *(const short8v*)((const char*)Alds + ((w * 32 + m * 16 + lr) * 64 + kb * 16));
#pragma unroll
    for (int n = 0; n < 5; ++n)
      b[n] = *(const short8v*)((const char*)Blds + ((n * 16 + lr) * 64 + kb * 16));
#pragma unroll
    for (int m = 0; m < 2; ++m)
#pragma unroll
      for (int n = 0; n < 5; ++n)
        acc[m][n] = __builtin_amdgcn_mfma_f32_16x16x32_bf16(a[m], b[n], acc[m][n], 0, 0, 0);
  }

  int lr = lane & 15, lq = lane >> 4;
#pragma unroll
  for (int m = 0; m < 2; ++m) {
#pragma unroll
    for (int r = 0; r < 4; ++r) {
      int rowg = m0 + w * 32 + m * 16 + lq * 4 + r;
      if (rowg < M) {
#pragma unroll
        for (int n = 0; n < 5; ++n) {
          int c = n * 16 + lr;
          float v = acc[m][n][r];
          if (c < CLS)
            pp[(size_t)rowg * CLS + c] = f2bf(v);
          else
            rr[(size_t)rowg * CLS + (c - CLS)] = v + b2[c - CLS];
        }
      }
    }
  }
}

// ---------------- final: mean-aggregate bf16 p, add rr, log_softmax -------
__global__ __launch_bounds__(256) void final_kernel(const int* __restrict__ rowptr,
                                                    const int* __restrict__ col,
                                                    const unsigned int* __restrict__ pp32,
                                                    const float* __restrict__ rr,
                                                    float* __restrict__ out, int N) {
  int wave = threadIdx.x >> 6, lane = threadIdx.x & 63;
  int row = blockIdx.x * 4 + wave;
  if (row >= N) return;
  int s0 = rowptr[row], s1 = rowptr[row + 1];
  bool active = lane < 20;
  float a0 = 0.f, a1 = 0.f;
  int j = s0;
  for (; j + 3 < s1; j += 4) {
    int c0 = col[j], c1 = col[j + 1], c2 = col[j + 2], c3 = col[j + 3];
    if (active) {
      unsigned int u0 = pp32[(size_t)c0 * 20 + lane];
      unsigned int u1 = pp32[(size_t)c1 * 20 + lane];
      unsigned int u2 = pp32[(size_t)c2 * 20 + lane];
      unsigned int u3 = pp32[(size_t)c3 * 20 + lane];
      a0 += (bf2f((unsigned short)u0) + bf2f((unsigned short)u1)) +
            (bf2f((unsigned short)u2) + bf2f((unsigned short)u3));
      a1 += (bf2f((unsigned short)(u0 >> 16)) + bf2f((unsigned short)(u1 >> 16))) +
            (bf2f((unsigned short)(u2 >> 16)) + bf2f((unsigned short)(u3 >> 16)));
    }
  }
  for (; j < s1; ++j) {
    int c = col[j];
    if (active) {
      unsigned int u = pp32[(size_t)c * 20 + lane];
      a0 += bf2f((unsigned short)u);
      a1 += bf2f((unsigned short)(u >> 16));
    }
  }
  float inv = 1.f / fmaxf((float)(s1 - s0), 1.f);
  float v0 = -1e30f, v1 = -1e30f;
  if (active) {
    float2 rv = *(const float2*)(rr + (size_t)row * CLS + lane * 2);
    v0 = a0 * inv + rv.x;
    v1 = a1 * inv + rv.y;
  }
  float mx = fmaxf(v0, v1);
#pragma unroll
  for (int d = 32; d >= 1; d >>= 1) mx = fmaxf(mx, __shfl_xor(mx, d, 64));
  float ex = active ? (expf(v0 - mx) + expf(v1 - mx)) : 0.f;
  float sum = ex;
#pragma unroll
  for (int d = 32; d >= 1; d >>= 1) sum += __shfl_xor(sum, d, 64);
  float ls = logf(sum);
  if (active) {
    float2 o;
    o.x = v0 - mx - ls;
    o.y = v1 - mx - ls;
    *(float2*)(out + (size_t)row * CLS + lane * 2) = o;
  }
}

// ---------------- host launcher ----------------
extern "C" void kernel_launch(void* const* d_in, const int* in_sizes, int n_in,
                              void* d_out, int out_size, void* d_ws, size_t ws_size,
                              hipStream_t stream) {
  (void)n_in; (void)out_size; (void)ws_size;
  const float* x   = (const float*)d_in[0];
  const int*   ei  = (const int*)d_in[1];
  const float* W1l = (const float*)d_in[2];
  const float* W1r = (const float*)d_in[3];
  const float* b1  = (const float*)d_in[4];
  const float* W2l = (const float*)d_in[5];
  const float* W2r = (const float*)d_in[6];
  const float* b2  = (const float*)d_in[7];
  float* out = (float*)d_out;

  const int N = in_sizes[0] / F_IN;
  const int E = in_sizes[1] / 2;
  const int Npad = (N + 127) & ~127;
  const int pstep = (N + NPART - 1) / NPART;

  char* ws = (char*)d_ws;
  size_t off = 0;
  auto alloc = [&](size_t bytes) -> void* {
    void* p = ws + off;
    off = (off + bytes + 255) & ~(size_t)255;
    return p;
  };
  int* flag    = (int*)alloc(4);
  int* cnt     = (int*)alloc((size_t)N * 4);
  int* bsum    = (int*)alloc(4096);
  int* rowptr  = (int*)alloc(((size_t)N + 1) * 4);
  int* cursor  = (int*)alloc((size_t)N * 4);
  int* csr_col = (int*)alloc((size_t)E * 4);
  unsigned short* xb   = (unsigned short*)alloc((size_t)Npad * F_IN * 2);
  unsigned short* aggb = (unsigned short*)alloc((size_t)Npad * F_IN * 2);
  unsigned short* W1t  = (unsigned short*)alloc((size_t)256 * 256 * 2);
  unsigned short* W2t  = (unsigned short*)alloc((size_t)80 * 256 * 2);
  unsigned short* hb   = (unsigned short*)alloc((size_t)Npad * HID * 2);
  unsigned short* pp   = (unsigned short*)alloc((size_t)N * CLS * 2);
  float* rr            = (float*)alloc((size_t)N * CLS * 4);

  hipMemsetAsync(cnt, 0, (size_t)N * 4, stream);
  detect_kernel<<<1, 64, 0, stream>>>(ei, flag);

  // 8 partition groups x 128 blocks each
  int part_blocks = NPART * 128;
  int nb = (N + 255) / 256;  // 391 <= 512 required by scan_bsum_kernel
  hist_part_kernel<<<part_blocks, 256, 0, stream>>>(ei, E, flag, cnt, pstep, N);
  blocksum_kernel<<<nb, 256, 0, stream>>>(cnt, bsum, N);
  scan_bsum_kernel<<<1, 512, 0, stream>>>(bsum, nb);
  scan_apply_kernel<<<nb, 256, 0, stream>>>(cnt, bsum, rowptr, cursor, N, E);
  scatter_part_kernel<<<part_blocks, 256, 0, stream>>>(ei, E, flag, cursor, csr_col,
                                                       pstep, N);

  long long n_elems = (long long)Npad * F_IN, n_valid = (long long)N * F_IN;
  cast_x_kernel<<<(int)((n_elems / 8 + 255) / 256), 256, 0, stream>>>(
      x, (unsigned int*)xb, n_elems, n_valid);
  cast_w1_kernel<<<(256 * 256 + 255) / 256, 256, 0, stream>>>(W1l, W1r, W1t);
  cast_w2_kernel<<<(80 * 256 + 255) / 256, 256, 0, stream>>>(W2l, W2r, W2t);

  agg1_kernel<<<(N + 3) / 4, 256, 0, stream>>>((const unsigned int*)xb, rowptr, csr_col,
                                               (unsigned int*)aggb, N);

  dim3 g1(Npad / 128, 2);
  gemm1_mfma<<<g1, 256, 0, stream>>>(aggb, xb, W1t, b1, hb, N);
  gemm2_mfma<<<Npad / 128, 256, 0, stream>>>(hb, W2t, b2, pp, rr, N);
  final_kernel<<<(N + 3) / 4, 256, 0, stream>>>(rowptr, csr_col, (const unsigned int*)pp,
                                                rr, out, N);
}

// Round 5
// 361.929 us; speedup vs baseline: 2.3381x; 1.0518x over previous
//
#include <hip/hip_runtime.h>
#include <math.h>

#define F_IN 128
#define HID  256
#define CLS  40
#define NPART 8

typedef __attribute__((ext_vector_type(8))) short short8v;   // 8 bf16 (4 VGPRs)
typedef __attribute__((ext_vector_type(4))) float f32x4;

#define GLB_AS(p) ((const __attribute__((address_space(1))) unsigned int*)(p))
#define LDS_AS(p) ((__attribute__((address_space(3))) unsigned int*)(p))

__device__ __forceinline__ float bf2f(unsigned short u) {
  unsigned int v = ((unsigned int)u) << 16;
  return __builtin_bit_cast(float, v);
}
__device__ __forceinline__ unsigned short f2bf(float f) {  // round-to-nearest-even
  unsigned int u = __builtin_bit_cast(unsigned int, f);
  u += 0x7fffu + ((u >> 16) & 1u);
  return (unsigned short)(u >> 16);
}

// ---------------- edge_index decode (int32 vs int64 hedge) ----------------
__global__ void detect_kernel(const int* __restrict__ ei, int* __restrict__ flag) {
  if (threadIdx.x == 0 && blockIdx.x == 0) {
    int ornz = 0;
    for (int i = 1; i < 256; i += 2) ornz |= ei[i];
    *flag = (ornz == 0) ? 1 : 0;
  }
}
__device__ __forceinline__ int edge_dst(const int* ei, int e, int E, int is64) {
  return is64 ? ei[2ll * E + 2ll * e] : ei[(long long)E + e];
}
__device__ __forceinline__ int edge_src(const int* ei, int e, int is64) {
  return is64 ? ei[2ll * e] : ei[e];
}

// ---------------- CSR build (DST-partitioned: partition = blockIdx & 7) ----
__global__ __launch_bounds__(256) void hist_part_kernel(const int* __restrict__ ei, int E,
                                                        const int* __restrict__ flag,
                                                        int* __restrict__ cnt, int pstep,
                                                        int N) {
  int pid = blockIdx.x & (NPART - 1);
  int lo = pid * pstep;
  int hi = min(lo + pstep, N);
  int is64 = *flag;
  int nblk = gridDim.x >> 3;
  int bslot = blockIdx.x >> 3;
  int stride = nblk * 256 * 2;
  for (int e = (bslot * 256 + threadIdx.x) * 2; e < E; e += stride) {
    int d0 = edge_dst(ei, e, E, is64);
    int d1 = edge_dst(ei, e + 1, E, is64);
    if (d0 >= lo && d0 < hi) atomicAdd(&cnt[d0], 1);
    if (d1 >= lo && d1 < hi) atomicAdd(&cnt[d1], 1);
  }
}

__global__ __launch_bounds__(256) void scatter_part_kernel(const int* __restrict__ ei, int E,
                                                           const int* __restrict__ flag,
                                                           int* __restrict__ cursor,
                                                           int* __restrict__ csr_col,
                                                           int pstep, int N) {
  int pid = blockIdx.x & (NPART - 1);
  int lo = pid * pstep;
  int hi = min(lo + pstep, N);
  int is64 = *flag;
  int nblk = gridDim.x >> 3;
  int bslot = blockIdx.x >> 3;
  int stride = nblk * 256 * 2;
  for (int e = (bslot * 256 + threadIdx.x) * 2; e < E; e += stride) {
    int d0 = edge_dst(ei, e, E, is64);
    int d1 = edge_dst(ei, e + 1, E, is64);
    if (d0 >= lo && d0 < hi) {
      int sv = edge_src(ei, e, is64);
      int pos = atomicAdd(&cursor[d0], 1);
      csr_col[pos] = sv;
    }
    if (d1 >= lo && d1 < hi) {
      int sv = edge_src(ei, e + 1, is64);
      int pos = atomicAdd(&cursor[d1], 1);
      csr_col[pos] = sv;
    }
  }
}

__global__ __launch_bounds__(256) void blocksum_kernel(const int* __restrict__ cnt,
                                                       int* __restrict__ bsum, int n) {
  __shared__ int s[256];
  int t = threadIdx.x;
  int i = blockIdx.x * 256 + t;
  s[t] = (i < n) ? cnt[i] : 0;
  __syncthreads();
  for (int d = 128; d > 0; d >>= 1) {
    if (t < d) s[t] += s[t + d];
    __syncthreads();
  }
  if (t == 0) bsum[blockIdx.x] = s[0];
}

__global__ __launch_bounds__(512) void scan_bsum_kernel(int* __restrict__ bsum, int nb) {
  __shared__ int s[512];
  int t = threadIdx.x;
  int v = (t < nb) ? bsum[t] : 0;
  s[t] = v;
  __syncthreads();
  for (int d = 1; d < 512; d <<= 1) {
    int xv = (t >= d) ? s[t - d] : 0;
    __syncthreads();
    s[t] += xv;
    __syncthreads();
  }
  if (t < nb) bsum[t] = s[t] - v;  // exclusive
}

__global__ __launch_bounds__(256) void scan_apply_kernel(const int* __restrict__ cnt,
                                                         const int* __restrict__ bsum,
                                                         int* __restrict__ rowptr,
                                                         int* __restrict__ cursor,
                                                         int N, int E) {
  __shared__ int s[256];
  int t = threadIdx.x;
  int i = blockIdx.x * 256 + t;
  int v = (i < N) ? cnt[i] : 0;
  s[t] = v;
  __syncthreads();
  for (int d = 1; d < 256; d <<= 1) {
    int xv = (t >= d) ? s[t - d] : 0;
    __syncthreads();
    s[t] += xv;
    __syncthreads();
  }
  int excl = s[t] - v + bsum[blockIdx.x];
  if (i < N) {
    rowptr[i] = excl;
    cursor[i] = excl;
  }
  if (i == N - 1) rowptr[N] = E;
}

// ---------------- casts ----------------
__global__ __launch_bounds__(256) void cast_x_kernel(const float* __restrict__ x,
                                                     unsigned int* __restrict__ xb32,
                                                     long long n_elems, long long n_valid) {
  long long base = ((long long)blockIdx.x * 256 + threadIdx.x) * 8;
  if (base >= n_elems) return;
  uint4 o;
  if (base < n_valid) {
    float4 v0 = *(const float4*)(x + base);
    float4 v1 = *(const float4*)(x + base + 4);
    o.x = (unsigned)f2bf(v0.x) | ((unsigned)f2bf(v0.y) << 16);
    o.y = (unsigned)f2bf(v0.z) | ((unsigned)f2bf(v0.w) << 16);
    o.z = (unsigned)f2bf(v1.x) | ((unsigned)f2bf(v1.y) << 16);
    o.w = (unsigned)f2bf(v1.z) | ((unsigned)f2bf(v1.w) << 16);
  } else {
    o = uint4{0, 0, 0, 0};
  }
  *(uint4*)(xb32 + (base >> 1)) = o;
}

// W1t[n][k] = bf16( k<128 ? W1l[k][n] : W1r[k-128][n] ), n<256, k<256
__global__ __launch_bounds__(256) void cast_w1_kernel(const float* __restrict__ W1l,
                                                      const float* __restrict__ W1r,
                                                      unsigned short* __restrict__ W1t) {
  int idx = blockIdx.x * 256 + threadIdx.x;
  if (idx >= 256 * 256) return;
  int n = idx >> 8, k = idx & 255;
  float v = (k < 128) ? W1l[(size_t)k * HID + n] : W1r[(size_t)(k - 128) * HID + n];
  W1t[(size_t)n * 256 + k] = f2bf(v);
}

// W2t[n][k] = bf16( n<40 ? W2l[k][n] : W2r[k][n-40] ), n<80, k<256
__global__ __launch_bounds__(256) void cast_w2_kernel(const float* __restrict__ W2l,
                                                      const float* __restrict__ W2r,
                                                      unsigned short* __restrict__ W2t) {
  int idx = blockIdx.x * 256 + threadIdx.x;
  if (idx >= 80 * 256) return;
  int n = idx >> 8, k = idx & 255;
  float v = (n < CLS) ? W2l[(size_t)k * CLS + n] : W2r[(size_t)k * CLS + (n - CLS)];
  W2t[(size_t)n * 256 + k] = f2bf(v);
}

// ---------------- layer-1 mean aggregation -------------------------------
// 4 edges per wide load: lane = slot(l>>4)*16 + piece(l&15); each lane loads
// uint4 (8 bf16 dims) of its slot's edge row; x2 unroll = 8 edges in flight.
// Slot-reduce via shfl_xor 16/32; lanes 0..15 write the packed bf16 row.
__global__ __launch_bounds__(256) void agg1_kernel(const uint4* __restrict__ xb4,
                                                   const int* __restrict__ rowptr,
                                                   const int* __restrict__ col,
                                                   uint4* __restrict__ aggb4, int N) {
  int wave = threadIdx.x >> 6, lane = threadIdx.x & 63;
  int row = blockIdx.x * 4 + wave;
  if (row >= N) return;
  int s0 = rowptr[row], s1 = rowptr[row + 1];
  int slot = lane >> 4, piece = lane & 15;
  float acc[8] = {};
  for (int j = s0; j < s1; j += 8) {
    int rem = s1 - j;
    if (slot < rem) {
      int c = col[j + slot];
      uint4 u = xb4[(size_t)c * 16 + piece];
      acc[0] += bf2f((unsigned short)u.x);
      acc[1] += bf2f((unsigned short)(u.x >> 16));
      acc[2] += bf2f((unsigned short)u.y);
      acc[3] += bf2f((unsigned short)(u.y >> 16));
      acc[4] += bf2f((unsigned short)u.z);
      acc[5] += bf2f((unsigned short)(u.z >> 16));
      acc[6] += bf2f((unsigned short)u.w);
      acc[7] += bf2f((unsigned short)(u.w >> 16));
    }
    if (slot + 4 < rem) {
      int c = col[j + slot + 4];
      uint4 u = xb4[(size_t)c * 16 + piece];
      acc[0] += bf2f((unsigned short)u.x);
      acc[1] += bf2f((unsigned short)(u.x >> 16));
      acc[2] += bf2f((unsigned short)u.y);
      acc[3] += bf2f((unsigned short)(u.y >> 16));
      acc[4] += bf2f((unsigned short)u.z);
      acc[5] += bf2f((unsigned short)(u.z >> 16));
      acc[6] += bf2f((unsigned short)u.w);
      acc[7] += bf2f((unsigned short)(u.w >> 16));
    }
  }
#pragma unroll
  for (int q = 0; q < 8; ++q) {
    acc[q] += __shfl_xor(acc[q], 16, 64);
    acc[q] += __shfl_xor(acc[q], 32, 64);
  }
  if (lane < 16) {
    float inv = 1.f / fmaxf((float)(s1 - s0), 1.f);
    uint4 o;
    o.x = (unsigned)f2bf(acc[0] * inv) | ((unsigned)f2bf(acc[1] * inv) << 16);
    o.y = (unsigned)f2bf(acc[2] * inv) | ((unsigned)f2bf(acc[3] * inv) << 16);
    o.z = (unsigned)f2bf(acc[4] * inv) | ((unsigned)f2bf(acc[5] * inv) << 16);
    o.w = (unsigned)f2bf(acc[6] * inv) | ((unsigned)f2bf(acc[7] * inv) << 16);
    aggb4[(size_t)row * 16 + piece] = o;
  }
}

// ---------------- GEMM1 (MFMA): hb = relu([aggb|xb] @ W1t^T + b1) ----------
__global__ __launch_bounds__(256) void gemm1_mfma(const unsigned short* __restrict__ aggb,
                                                  const unsigned short* __restrict__ xb,
                                                  const unsigned short* __restrict__ W1t,
                                                  const float* __restrict__ b1,
                                                  unsigned short* __restrict__ hb, int M) {
  __shared__ unsigned short Alds[128 * 32];
  __shared__ unsigned short Blds[128 * 32];
  int t = threadIdx.x, lane = t & 63, w = t >> 6;
  int wm = w >> 1, wn = w & 1;
  int m0 = blockIdx.x * 128, n0 = blockIdx.y * 128;
  f32x4 acc[4][4] = {};

  for (int k0 = 0; k0 < 256; k0 += 32) {
    const unsigned short* Asrc = (k0 < 128) ? aggb : xb;
    int keff = k0 & 127;
    __syncthreads();
#pragma unroll
    for (int j = 0; j < 2; ++j) {
      int g = (w * 2 + j) * 64 + lane;
      int row = g >> 2, kb = g & 3;
      const char* gp = (const char*)Asrc + ((size_t)(m0 + row) * 128 + keff) * 2 + kb * 16;
      __builtin_amdgcn_global_load_lds(GLB_AS(gp),
                                       LDS_AS((char*)Alds + (w * 2 + j) * 1024), 16, 0, 0);
    }
#pragma unroll
    for (int j = 0; j < 2; ++j) {
      int g = (w * 2 + j) * 64 + lane;
      int n = g >> 2, kb = g & 3;
      const char* gp = (const char*)W1t + ((size_t)(n0 + n) * 256 + k0) * 2 + kb * 16;
      __builtin_amdgcn_global_load_lds(GLB_AS(gp),
                                       LDS_AS((char*)Blds + (w * 2 + j) * 1024), 16, 0, 0);
    }
    __syncthreads();

    int lr = lane & 15, kb = lane >> 4;
    short8v a[4], b[4];
#pragma unroll
    for (int m = 0; m < 4; ++m)
      a[m] = *(const short8v*)((const char*)Alds + ((wm * 64 + m * 16 + lr) * 64 + kb * 16));
#pragma unroll
    for (int n = 0; n < 4; ++n)
      b[n] = *(const short8v*)((const char*)Blds + ((wn * 64 + n * 16 + lr) * 64 + kb * 16));
#pragma unroll
    for (int m = 0; m < 4; ++m)
#pragma unroll
      for (int n = 0; n < 4; ++n)
        acc[m][n] = __builtin_amdgcn_mfma_f32_16x16x32_bf16(a[m], b[n], acc[m][n], 0, 0, 0);
  }

  int lr = lane & 15, lq = lane >> 4;
#pragma unroll
  for (int n = 0; n < 4; ++n) {
    int col = n0 + wn * 64 + n * 16 + lr;
    float bias = b1[col];
#pragma unroll
    for (int m = 0; m < 4; ++m) {
#pragma unroll
      for (int r = 0; r < 4; ++r) {
        int rowg = m0 + wm * 64 + m * 16 + lq * 4 + r;
        if (rowg < M)
          hb[(size_t)rowg * 256 + col] = f2bf(fmaxf(acc[m][n][r] + bias, 0.f));
      }
    }
  }
}

// ---------------- GEMM2 (MFMA): [p|r] = hb @ W2t^T ------------------------
__global__ __launch_bounds__(256) void gemm2_mfma(const unsigned short* __restrict__ hb,
                                                  const unsigned short* __restrict__ W2t,
                                                  const float* __restrict__ b2,
                                                  unsigned short* __restrict__ pp,
                                                  float* __restrict__ rr, int M) {
  __shared__ unsigned short Alds[128 * 32];
  __shared__ unsigned short Blds[80 * 32];
  int t = threadIdx.x, lane = t & 63, w = t >> 6;
  int m0 = blockIdx.x * 128;
  f32x4 acc[2][5] = {};

  for (int k0 = 0; k0 < 256; k0 += 32) {
    __syncthreads();
#pragma unroll
    for (int j = 0; j < 2; ++j) {
      int g = (w * 2 + j) * 64 + lane;
      int row = g >> 2, kb = g & 3;
      const char* gp = (const char*)hb + ((size_t)(m0 + row) * 256 + k0) * 2 + kb * 16;
      __builtin_amdgcn_global_load_lds(GLB_AS(gp),
                                       LDS_AS((char*)Alds + (w * 2 + j) * 1024), 16, 0, 0);
    }
    int nissue = (w == 0) ? 2 : 1;
    for (int jj = 0; jj < nissue; ++jj) {
      int issue = (jj == 0) ? w : 4;
      int g = issue * 64 + lane;
      int n = g >> 2, kb = g & 3;
      const char* gp = (const char*)W2t + ((size_t)n * 256 + k0) * 2 + kb * 16;
      __builtin_amdgcn_global_load_lds(GLB_AS(gp),
                                       LDS_AS((char*)Blds + issue * 1024), 16, 0, 0);
    }
    __syncthreads();

    int lr = lane & 15, kb = lane >> 4;
    short8v a[2], b[5];
#pragma unroll
    for (int m = 0; m < 2; ++m)
      a[m] = *(const short8v*)((const char*)Alds + ((w * 32 + m * 16 + lr) * 64 + kb * 16));
#pragma unroll
    for (int n = 0; n < 5; ++n)
      b[n] = *(const short8v*)((const char*)Blds + ((n * 16 + lr) * 64 + kb * 16));
#pragma unroll
    for (int m = 0; m < 2; ++m)
#pragma unroll
      for (int n = 0; n < 5; ++n)
        acc[m][n] = __builtin_amdgcn_mfma_f32_16x16x32_bf16(a[m], b[n], acc[m][n], 0, 0, 0);
  }

  int lr = lane & 15, lq = lane >> 4;
#pragma unroll
  for (int m = 0; m < 2; ++m) {
#pragma unroll
    for (int r = 0; r < 4; ++r) {
      int rowg = m0 + w * 32 + m * 16 + lq * 4 + r;
      if (rowg < M) {
#pragma unroll
        for (int n = 0; n < 5; ++n) {
          int c = n * 16 + lr;
          float v = acc[m][n][r];
          if (c < CLS)
            pp[(size_t)rowg * CLS + c] = f2bf(v);
          else
            rr[(size_t)rowg * CLS + (c - CLS)] = v + b2[c - CLS];
        }
      }
    }
  }
}

// ---------------- final: mean-aggregate bf16 p, add rr, log_softmax -------
// pp row = 5 x uint4 (80B). lane = slot(l/5)*5 + piece(l%5), slots 0..7 (40
// lanes); each lane loads uint4 = 8 classes of its slot's edge; x2 unroll =
// 16 edges in flight. Slot-reduce strides 20/10/5 -> lanes 0..4 own 8 classes.
__global__ __launch_bounds__(256) void final_kernel(const int* __restrict__ rowptr,
                                                    const int* __restrict__ col,
                                                    const uint4* __restrict__ pp4,
                                                    const float* __restrict__ rr,
                                                    float* __restrict__ out, int N) {
  int wave = threadIdx.x >> 6, lane = threadIdx.x & 63;
  int row = blockIdx.x * 4 + wave;
  if (row >= N) return;
  int s0 = rowptr[row], s1 = rowptr[row + 1];
  int slot = lane / 5;
  int piece = lane - slot * 5;
  bool l40 = lane < 40;
  float acc[8] = {};
  for (int j = s0; j < s1; j += 16) {
    int rem = s1 - j;
    if (l40 && slot < rem) {
      int c = col[j + slot];
      uint4 u = pp4[(size_t)c * 5 + piece];
      acc[0] += bf2f((unsigned short)u.x);
      acc[1] += bf2f((unsigned short)(u.x >> 16));
      acc[2] += bf2f((unsigned short)u.y);
      acc[3] += bf2f((unsigned short)(u.y >> 16));
      acc[4] += bf2f((unsigned short)u.z);
      acc[5] += bf2f((unsigned short)(u.z >> 16));
      acc[6] += bf2f((unsigned short)u.w);
      acc[7] += bf2f((unsigned short)(u.w >> 16));
    }
    if (l40 && slot + 8 < rem) {
      int c = col[j + slot + 8];
      uint4 u = pp4[(size_t)c * 5 + piece];
      acc[0] += bf2f((unsigned short)u.x);
      acc[1] += bf2f((unsigned short)(u.x >> 16));
      acc[2] += bf2f((unsigned short)u.y);
      acc[3] += bf2f((unsigned short)(u.y >> 16));
      acc[4] += bf2f((unsigned short)u.z);
      acc[5] += bf2f((unsigned short)(u.z >> 16));
      acc[6] += bf2f((unsigned short)u.w);
      acc[7] += bf2f((unsigned short)(u.w >> 16));
    }
  }
  // reduce slots: lanes 0..4 end with sum over slots 0..7 (lanes 40..63 hold
  // zero acc; dataflow into lanes 0..4 only references lanes < 40)
#pragma unroll
  for (int q = 0; q < 8; ++q) {
    float v = acc[q];
    v += __shfl(v, lane + 20, 64);
    v += __shfl(v, lane + 10, 64);
    v += __shfl(v, lane + 5, 64);
    acc[q] = v;
  }
  float inv = 1.f / fmaxf((float)(s1 - s0), 1.f);
  bool owner = lane < 5;
  float v[8];
  float m8 = -1e30f;
  if (owner) {
    const float* rrow = rr + (size_t)row * CLS + lane * 8;
    float4 ra = *(const float4*)rrow;
    float4 rb = *(const float4*)(rrow + 4);
    v[0] = acc[0] * inv + ra.x;
    v[1] = acc[1] * inv + ra.y;
    v[2] = acc[2] * inv + ra.z;
    v[3] = acc[3] * inv + ra.w;
    v[4] = acc[4] * inv + rb.x;
    v[5] = acc[5] * inv + rb.y;
    v[6] = acc[6] * inv + rb.z;
    v[7] = acc[7] * inv + rb.w;
#pragma unroll
    for (int q = 0; q < 8; ++q) m8 = fmaxf(m8, v[q]);
  } else {
#pragma unroll
    for (int q = 0; q < 8; ++q) v[q] = 0.f;
  }
  float mx = -1e30f;
#pragma unroll
  for (int p = 0; p < 5; ++p) mx = fmaxf(mx, __shfl(m8, p, 64));
  float lsum = 0.f;
  if (owner) {
#pragma unroll
    for (int q = 0; q < 8; ++q) lsum += expf(v[q] - mx);
  }
  float sum = 0.f;
#pragma unroll
  for (int p = 0; p < 5; ++p) sum += __shfl(lsum, p, 64);
  float ls = logf(sum);
  if (owner) {
    float* orow = out + (size_t)row * CLS + lane * 8;
    float4 o0, o1;
    o0.x = v[0] - mx - ls;
    o0.y = v[1] - mx - ls;
    o0.z = v[2] - mx - ls;
    o0.w = v[3] - mx - ls;
    o1.x = v[4] - mx - ls;
    o1.y = v[5] - mx - ls;
    o1.z = v[6] - mx - ls;
    o1.w = v[7] - mx - ls;
    *(float4*)orow = o0;
    *(float4*)(orow + 4) = o1;
  }
}

// ---------------- host launcher ----------------
extern "C" void kernel_launch(void* const* d_in, const int* in_sizes, int n_in,
                              void* d_out, int out_size, void* d_ws, size_t ws_size,
                              hipStream_t stream) {
  (void)n_in; (void)out_size; (void)ws_size;
  const float* x   = (const float*)d_in[0];
  const int*   ei  = (const int*)d_in[1];
  const float* W1l = (const float*)d_in[2];
  const float* W1r = (const float*)d_in[3];
  const float* b1  = (const float*)d_in[4];
  const float* W2l = (const float*)d_in[5];
  const float* W2r = (const float*)d_in[6];
  const float* b2  = (const float*)d_in[7];
  float* out = (float*)d_out;

  const int N = in_sizes[0] / F_IN;
  const int E = in_sizes[1] / 2;
  const int Npad = (N + 127) & ~127;
  const int pstep = (N + NPART - 1) / NPART;

  char* ws = (char*)d_ws;
  size_t off = 0;
  auto alloc = [&](size_t bytes) -> void* {
    void* p = ws + off;
    off = (off + bytes + 255) & ~(size_t)255;
    return p;
  };
  int* flag    = (int*)alloc(4);
  int* cnt     = (int*)alloc((size_t)N * 4);
  int* bsum    = (int*)alloc(4096);
  int* rowptr  = (int*)alloc(((size_t)N + 1) * 4);
  int* cursor  = (int*)alloc((size_t)N * 4);
  int* csr_col = (int*)alloc((size_t)E * 4);
  unsigned short* xb   = (unsigned short*)alloc((size_t)Npad * F_IN * 2);
  unsigned short* aggb = (unsigned short*)alloc((size_t)Npad * F_IN * 2);
  unsigned short* W1t  = (unsigned short*)alloc((size_t)256 * 256 * 2);
  unsigned short* W2t  = (unsigned short*)alloc((size_t)80 * 256 * 2);
  unsigned short* hb   = (unsigned short*)alloc((size_t)Npad * HID * 2);
  unsigned short* pp   = (unsigned short*)alloc((size_t)N * CLS * 2);
  float* rr            = (float*)alloc((size_t)N * CLS * 4);

  hipMemsetAsync(cnt, 0, (size_t)N * 4, stream);
  detect_kernel<<<1, 64, 0, stream>>>(ei, flag);

  int part_blocks = NPART * 128;
  int nb = (N + 255) / 256;  // 391 <= 512 required by scan_bsum_kernel
  hist_part_kernel<<<part_blocks, 256, 0, stream>>>(ei, E, flag, cnt, pstep, N);
  blocksum_kernel<<<nb, 256, 0, stream>>>(cnt, bsum, N);
  scan_bsum_kernel<<<1, 512, 0, stream>>>(bsum, nb);
  scan_apply_kernel<<<nb, 256, 0, stream>>>(cnt, bsum, rowptr, cursor, N, E);
  scatter_part_kernel<<<part_blocks, 256, 0, stream>>>(ei, E, flag, cursor, csr_col,
                                                       pstep, N);

  long long n_elems = (long long)Npad * F_IN, n_valid = (long long)N * F_IN;
  cast_x_kernel<<<(int)((n_elems / 8 + 255) / 256), 256, 0, stream>>>(
      x, (unsigned int*)xb, n_elems, n_valid);
  cast_w1_kernel<<<(256 * 256 + 255) / 256, 256, 0, stream>>>(W1l, W1r, W1t);
  cast_w2_kernel<<<(80 * 256 + 255) / 256, 256, 0, stream>>>(W2l, W2r, W2t);

  agg1_kernel<<<(N + 3) / 4, 256, 0, stream>>>((const uint4*)xb, rowptr, csr_col,
                                               (uint4*)aggb, N);

  dim3 g1(Npad / 128, 2);
  gemm1_mfma<<<g1, 256, 0, stream>>>(aggb, xb, W1t, b1, hb, N);
  gemm2_mfma<<<Npad / 128, 256, 0, stream>>>(hb, W2t, b2, pp, rr, N);
  final_kernel<<<(N + 3) / 4, 256, 0, stream>>>(rowptr, csr_col, (const uint4*)pp,
                                                rr, out, N);
}

// Round 6
// 346.284 us; speedup vs baseline: 2.4438x; 1.0452x over previous
//
#include <hip/hip_runtime.h>
#include <math.h>

#define F_IN 128
#define HID  256
#define CLS  40
#define NPART 8
#define EDGE_BLOCKS 2048           // 8 partitions x 256 blocks
#define CASTX_BLOCKS 1024

typedef __attribute__((ext_vector_type(8))) short short8v;   // 8 bf16 (4 VGPRs)
typedef __attribute__((ext_vector_type(4))) float f32x4;

#define GLB_AS(p) ((const __attribute__((address_space(1))) unsigned int*)(p))
#define LDS_AS(p) ((__attribute__((address_space(3))) unsigned int*)(p))

__device__ __forceinline__ float bf2f(unsigned short u) {
  unsigned int v = ((unsigned int)u) << 16;
  return __builtin_bit_cast(float, v);
}
__device__ __forceinline__ unsigned short f2bf(float f) {  // round-to-nearest-even
  unsigned int u = __builtin_bit_cast(unsigned int, f);
  u += 0x7fffu + ((u >> 16) & 1u);
  return (unsigned short)(u >> 16);
}

// int64 vs int32 edge layout: if int64 ([2,E] LE, ids < 2^31) every odd dword
// is a zero high-half. 8 random ids all zero: P ~ 1e-40. Uniform s_loads.
__device__ __forceinline__ int detect_is64(const int* __restrict__ ei) {
  int ornz = 0;
#pragma unroll
  for (int i = 1; i < 16; i += 2) ornz |= ei[i];
  return ornz == 0;
}
__device__ __forceinline__ int edge_dst(const int* ei, long long e, int E, int is64) {
  return is64 ? ei[2ll * E + 2ll * e] : ei[(long long)E + e];
}
__device__ __forceinline__ int edge_src(const int* ei, long long e, int is64) {
  return is64 ? ei[2ll * e] : ei[e];
}

// ---------------- phase A: hist (blocks 0..2047) + cast_x (rest) ----------
__global__ __launch_bounds__(256) void phaseA_kernel(const int* __restrict__ ei, int E,
                                                     int* __restrict__ cnt, int pstep, int N,
                                                     const float* __restrict__ x,
                                                     unsigned int* __restrict__ xb32,
                                                     long long n_elems, long long n_valid) {
  if (blockIdx.x < EDGE_BLOCKS) {
    // DST-partitioned histogram; partition = blockIdx & 7 (XCD-local writes)
    int is64 = detect_is64(ei);
    int pid = blockIdx.x & (NPART - 1);
    int lo = pid * pstep;
    int hi = min(lo + pstep, N);
    int bslot = blockIdx.x >> 3;                       // 0..255 within group
    const int NB = EDGE_BLOCKS / NPART;                // 256
    long long base = ((long long)bslot * 256 + threadIdx.x) * 4;
    long long stride = (long long)NB * 256 * 4;
    for (long long e = base; e < E; e += stride) {
      int d[4];
#pragma unroll
      for (int q = 0; q < 4; ++q)
        d[q] = (e + q < E) ? edge_dst(ei, e + q, E, is64) : -1;
#pragma unroll
      for (int q = 0; q < 4; ++q)
        if (d[q] >= lo && d[q] < hi) atomicAdd(&cnt[d[q]], 1);
    }
  } else {
    // cast x fp32 -> bf16 packed, grid-stride; zero pad rows [N, Npad)
    long long t0 = ((long long)(blockIdx.x - EDGE_BLOCKS) * 256 + threadIdx.x) * 8;
    long long stride = (long long)CASTX_BLOCKS * 256 * 8;
    for (long long base = t0; base < n_elems; base += stride) {
      uint4 o;
      if (base < n_valid) {
        float4 v0 = *(const float4*)(x + base);
        float4 v1 = *(const float4*)(x + base + 4);
        o.x = (unsigned)f2bf(v0.x) | ((unsigned)f2bf(v0.y) << 16);
        o.y = (unsigned)f2bf(v0.z) | ((unsigned)f2bf(v0.w) << 16);
        o.z = (unsigned)f2bf(v1.x) | ((unsigned)f2bf(v1.y) << 16);
        o.w = (unsigned)f2bf(v1.z) | ((unsigned)f2bf(v1.w) << 16);
      } else {
        o = uint4{0, 0, 0, 0};
      }
      *(uint4*)(xb32 + (base >> 1)) = o;
    }
  }
}

// ---------------- phase B: scatter (0..2047) + cast_w1 + cast_w2 ----------
__global__ __launch_bounds__(256) void phaseB_kernel(const int* __restrict__ ei, int E,
                                                     int* __restrict__ cursor,
                                                     int* __restrict__ csr_col,
                                                     int pstep, int N,
                                                     const float* __restrict__ W1l,
                                                     const float* __restrict__ W1r,
                                                     unsigned short* __restrict__ W1t,
                                                     const float* __restrict__ W2l,
                                                     const float* __restrict__ W2r,
                                                     unsigned short* __restrict__ W2t) {
  if (blockIdx.x < EDGE_BLOCKS) {
    int is64 = detect_is64(ei);
    int pid = blockIdx.x & (NPART - 1);
    int lo = pid * pstep;
    int hi = min(lo + pstep, N);
    int bslot = blockIdx.x >> 3;
    const int NB = EDGE_BLOCKS / NPART;
    long long base = ((long long)bslot * 256 + threadIdx.x) * 4;
    long long stride = (long long)NB * 256 * 4;
    for (long long e = base; e < E; e += stride) {
      int d[4];
#pragma unroll
      for (int q = 0; q < 4; ++q)
        d[q] = (e + q < E) ? edge_dst(ei, e + q, E, is64) : -1;
#pragma unroll
      for (int q = 0; q < 4; ++q) {
        if (d[q] >= lo && d[q] < hi) {
          int sv = edge_src(ei, e + q, is64);          // independent of atomic
          int pos = atomicAdd(&cursor[d[q]], 1);
          csr_col[pos] = sv;
        }
      }
    }
  } else if (blockIdx.x < EDGE_BLOCKS + 256) {
    // W1t[n][k] = bf16( k<128 ? W1l[k][n] : W1r[k-128][n] )
    int idx = (blockIdx.x - EDGE_BLOCKS) * 256 + threadIdx.x;
    int n = idx >> 8, k = idx & 255;
    float v = (k < 128) ? W1l[(size_t)k * HID + n] : W1r[(size_t)(k - 128) * HID + n];
    W1t[(size_t)n * 256 + k] = f2bf(v);
  } else {
    // W2t[n][k] = bf16( n<40 ? W2l[k][n] : W2r[k][n-40] )
    int idx = (blockIdx.x - EDGE_BLOCKS - 256) * 256 + threadIdx.x;
    int n = idx >> 8, k = idx & 255;
    float v = (n < CLS) ? W2l[(size_t)k * CLS + n] : W2r[(size_t)k * CLS + (n - CLS)];
    W2t[(size_t)n * 256 + k] = f2bf(v);
  }
}

// ---------------- prefix-scan chain ----------------
__global__ __launch_bounds__(256) void blocksum_kernel(const int* __restrict__ cnt,
                                                       int* __restrict__ bsum, int n) {
  __shared__ int s[256];
  int t = threadIdx.x;
  int i = blockIdx.x * 256 + t;
  s[t] = (i < n) ? cnt[i] : 0;
  __syncthreads();
  for (int d = 128; d > 0; d >>= 1) {
    if (t < d) s[t] += s[t + d];
    __syncthreads();
  }
  if (t == 0) bsum[blockIdx.x] = s[0];
}

__global__ __launch_bounds__(512) void scan_bsum_kernel(int* __restrict__ bsum, int nb) {
  __shared__ int s[512];
  int t = threadIdx.x;
  int v = (t < nb) ? bsum[t] : 0;
  s[t] = v;
  __syncthreads();
  for (int d = 1; d < 512; d <<= 1) {
    int xv = (t >= d) ? s[t - d] : 0;
    __syncthreads();
    s[t] += xv;
    __syncthreads();
  }
  if (t < nb) bsum[t] = s[t] - v;  // exclusive
}

__global__ __launch_bounds__(256) void scan_apply_kernel(const int* __restrict__ cnt,
                                                         const int* __restrict__ bsum,
                                                         int* __restrict__ rowptr,
                                                         int* __restrict__ cursor,
                                                         int N, int E) {
  __shared__ int s[256];
  int t = threadIdx.x;
  int i = blockIdx.x * 256 + t;
  int v = (i < N) ? cnt[i] : 0;
  s[t] = v;
  __syncthreads();
  for (int d = 1; d < 256; d <<= 1) {
    int xv = (t >= d) ? s[t - d] : 0;
    __syncthreads();
    s[t] += xv;
    __syncthreads();
  }
  int excl = s[t] - v + bsum[blockIdx.x];
  if (i < N) {
    rowptr[i] = excl;
    cursor[i] = excl;
  }
  if (i == N - 1) rowptr[N] = E;
}

// ---------------- layer-1 mean aggregation -------------------------------
// 4 edges per wide load: lane = slot(l>>4)*16 + piece(l&15); x2 unroll.
__global__ __launch_bounds__(256) void agg1_kernel(const uint4* __restrict__ xb4,
                                                   const int* __restrict__ rowptr,
                                                   const int* __restrict__ col,
                                                   uint4* __restrict__ aggb4, int N) {
  int wave = threadIdx.x >> 6, lane = threadIdx.x & 63;
  int row = blockIdx.x * 4 + wave;
  if (row >= N) return;
  int s0 = rowptr[row], s1 = rowptr[row + 1];
  int slot = lane >> 4, piece = lane & 15;
  float acc[8] = {};
  for (int j = s0; j < s1; j += 8) {
    int rem = s1 - j;
    if (slot < rem) {
      int c = col[j + slot];
      uint4 u = xb4[(size_t)c * 16 + piece];
      acc[0] += bf2f((unsigned short)u.x);
      acc[1] += bf2f((unsigned short)(u.x >> 16));
      acc[2] += bf2f((unsigned short)u.y);
      acc[3] += bf2f((unsigned short)(u.y >> 16));
      acc[4] += bf2f((unsigned short)u.z);
      acc[5] += bf2f((unsigned short)(u.z >> 16));
      acc[6] += bf2f((unsigned short)u.w);
      acc[7] += bf2f((unsigned short)(u.w >> 16));
    }
    if (slot + 4 < rem) {
      int c = col[j + slot + 4];
      uint4 u = xb4[(size_t)c * 16 + piece];
      acc[0] += bf2f((unsigned short)u.x);
      acc[1] += bf2f((unsigned short)(u.x >> 16));
      acc[2] += bf2f((unsigned short)u.y);
      acc[3] += bf2f((unsigned short)(u.y >> 16));
      acc[4] += bf2f((unsigned short)u.z);
      acc[5] += bf2f((unsigned short)(u.z >> 16));
      acc[6] += bf2f((unsigned short)u.w);
      acc[7] += bf2f((unsigned short)(u.w >> 16));
    }
  }
#pragma unroll
  for (int q = 0; q < 8; ++q) {
    acc[q] += __shfl_xor(acc[q], 16, 64);
    acc[q] += __shfl_xor(acc[q], 32, 64);
  }
  if (lane < 16) {
    float inv = 1.f / fmaxf((float)(s1 - s0), 1.f);
    uint4 o;
    o.x = (unsigned)f2bf(acc[0] * inv) | ((unsigned)f2bf(acc[1] * inv) << 16);
    o.y = (unsigned)f2bf(acc[2] * inv) | ((unsigned)f2bf(acc[3] * inv) << 16);
    o.z = (unsigned)f2bf(acc[4] * inv) | ((unsigned)f2bf(acc[5] * inv) << 16);
    o.w = (unsigned)f2bf(acc[6] * inv) | ((unsigned)f2bf(acc[7] * inv) << 16);
    aggb4[(size_t)row * 16 + piece] = o;
  }
}

// ---------------- GEMM1 (MFMA): hb = relu([aggb|xb] @ W1t^T + b1) ----------
__global__ __launch_bounds__(256) void gemm1_mfma(const unsigned short* __restrict__ aggb,
                                                  const unsigned short* __restrict__ xb,
                                                  const unsigned short* __restrict__ W1t,
                                                  const float* __restrict__ b1,
                                                  unsigned short* __restrict__ hb, int M) {
  __shared__ unsigned short Alds[128 * 32];
  __shared__ unsigned short Blds[128 * 32];
  int t = threadIdx.x, lane = t & 63, w = t >> 6;
  int wm = w >> 1, wn = w & 1;
  int m0 = blockIdx.x * 128, n0 = blockIdx.y * 128;
  f32x4 acc[4][4] = {};

  for (int k0 = 0; k0 < 256; k0 += 32) {
    const unsigned short* Asrc = (k0 < 128) ? aggb : xb;
    int keff = k0 & 127;
    __syncthreads();
#pragma unroll
    for (int j = 0; j < 2; ++j) {
      int g = (w * 2 + j) * 64 + lane;
      int row = g >> 2, kb = g & 3;
      const char* gp = (const char*)Asrc + ((size_t)(m0 + row) * 128 + keff) * 2 + kb * 16;
      __builtin_amdgcn_global_load_lds(GLB_AS(gp),
                                       LDS_AS((char*)Alds + (w * 2 + j) * 1024), 16, 0, 0);
    }
#pragma unroll
    for (int j = 0; j < 2; ++j) {
      int g = (w * 2 + j) * 64 + lane;
      int n = g >> 2, kb = g & 3;
      const char* gp = (const char*)W1t + ((size_t)(n0 + n) * 256 + k0) * 2 + kb * 16;
      __builtin_amdgcn_global_load_lds(GLB_AS(gp),
                                       LDS_AS((char*)Blds + (w * 2 + j) * 1024), 16, 0, 0);
    }
    __syncthreads();

    int lr = lane & 15, kb = lane >> 4;
    short8v a[4], b[4];
#pragma unroll
    for (int m = 0; m < 4; ++m)
      a[m] = *(const short8v*)((const char*)Alds + ((wm * 64 + m * 16 + lr) * 64 + kb * 16));
#pragma unroll
    for (int n = 0; n < 4; ++n)
      b[n] = *(const short8v*)((const char*)Blds + ((wn * 64 + n * 16 + lr) * 64 + kb * 16));
#pragma unroll
    for (int m = 0; m < 4; ++m)
#pragma unroll
      for (int n = 0; n < 4; ++n)
        acc[m][n] = __builtin_amdgcn_mfma_f32_16x16x32_bf16(a[m], b[n], acc[m][n], 0, 0, 0);
  }

  int lr = lane & 15, lq = lane >> 4;
#pragma unroll
  for (int n = 0; n < 4; ++n) {
    int col = n0 + wn * 64 + n * 16 + lr;
    float bias = b1[col];
#pragma unroll
    for (int m = 0; m < 4; ++m) {
#pragma unroll
      for (int r = 0; r < 4; ++r) {
        int rowg = m0 + wm * 64 + m * 16 + lq * 4 + r;
        if (rowg < M)
          hb[(size_t)rowg * 256 + col] = f2bf(fmaxf(acc[m][n][r] + bias, 0.f));
      }
    }
  }
}

// ---------------- GEMM2 (MFMA): [p|r] = hb @ W2t^T ------------------------
__global__ __launch_bounds__(256) void gemm2_mfma(const unsigned short* __restrict__ hb,
                                                  const unsigned short* __restrict__ W2t,
                                                  const float* __restrict__ b2,
                                                  unsigned short* __restrict__ pp,
                                                  float* __restrict__ rr, int M) {
  __shared__ unsigned short Alds[128 * 32];
  __shared__ unsigned short Blds[80 * 32];
  int t = threadIdx.x, lane = t & 63, w = t >> 6;
  int m0 = blockIdx.x * 128;
  f32x4 acc[2][5] = {};

  for (int k0 = 0; k0 < 256; k0 += 32) {
    __syncthreads();
#pragma unroll
    for (int j = 0; j < 2; ++j) {
      int g = (w * 2 + j) * 64 + lane;
      int row = g >> 2, kb = g & 3;
      const char* gp = (const char*)hb + ((size_t)(m0 + row) * 256 + k0) * 2 + kb * 16;
      __builtin_amdgcn_global_load_lds(GLB_AS(gp),
                                       LDS_AS((char*)Alds + (w * 2 + j) * 1024), 16, 0, 0);
    }
    int nissue = (w == 0) ? 2 : 1;
    for (int jj = 0; jj < nissue; ++jj) {
      int issue = (jj == 0) ? w : 4;
      int g = issue * 64 + lane;
      int n = g >> 2, kb = g & 3;
      const char* gp = (const char*)W2t + ((size_t)n * 256 + k0) * 2 + kb * 16;
      __builtin_amdgcn_global_load_lds(GLB_AS(gp),
                                       LDS_AS((char*)Blds + issue * 1024), 16, 0, 0);
    }
    __syncthreads();

    int lr = lane & 15, kb = lane >> 4;
    short8v a[2], b[5];
#pragma unroll
    for (int m = 0; m < 2; ++m)
      a[m] = *(const short8v*)((const char*)Alds + ((w * 32 + m * 16 + lr) * 64 + kb * 16));
#pragma unroll
    for (int n = 0; n < 5; ++n)
      b[n] = *(const short8v*)((const char*)Blds + ((n * 16 + lr) * 64 + kb * 16));
#pragma unroll
    for (int m = 0; m < 2; ++m)
#pragma unroll
      for (int n = 0; n < 5; ++n)
        acc[m][n] = __builtin_amdgcn_mfma_f32_16x16x32_bf16(a[m], b[n], acc[m][n], 0, 0, 0);
  }

  int lr = lane & 15, lq = lane >> 4;
#pragma unroll
  for (int m = 0; m < 2; ++m) {
#pragma unroll
    for (int r = 0; r < 4; ++r) {
      int rowg = m0 + w * 32 + m * 16 + lq * 4 + r;
      if (rowg < M) {
#pragma unroll
        for (int n = 0; n < 5; ++n) {
          int c = n * 16 + lr;
          float v = acc[m][n][r];
          if (c < CLS)
            pp[(size_t)rowg * CLS + c] = f2bf(v);
          else
            rr[(size_t)rowg * CLS + (c - CLS)] = v + b2[c - CLS];
        }
      }
    }
  }
}

// ---------------- final: mean-aggregate bf16 p, add rr, log_softmax -------
__global__ __launch_bounds__(256) void final_kernel(const int* __restrict__ rowptr,
                                                    const int* __restrict__ col,
                                                    const uint4* __restrict__ pp4,
                                                    const float* __restrict__ rr,
                                                    float* __restrict__ out, int N) {
  int wave = threadIdx.x >> 6, lane = threadIdx.x & 63;
  int row = blockIdx.x * 4 + wave;
  if (row >= N) return;
  int s0 = rowptr[row], s1 = rowptr[row + 1];
  int slot = lane / 5;
  int piece = lane - slot * 5;
  bool l40 = lane < 40;
  float acc[8] = {};
  for (int j = s0; j < s1; j += 16) {
    int rem = s1 - j;
    if (l40 && slot < rem) {
      int c = col[j + slot];
      uint4 u = pp4[(size_t)c * 5 + piece];
      acc[0] += bf2f((unsigned short)u.x);
      acc[1] += bf2f((unsigned short)(u.x >> 16));
      acc[2] += bf2f((unsigned short)u.y);
      acc[3] += bf2f((unsigned short)(u.y >> 16));
      acc[4] += bf2f((unsigned short)u.z);
      acc[5] += bf2f((unsigned short)(u.z >> 16));
      acc[6] += bf2f((unsigned short)u.w);
      acc[7] += bf2f((unsigned short)(u.w >> 16));
    }
    if (l40 && slot + 8 < rem) {
      int c = col[j + slot + 8];
      uint4 u = pp4[(size_t)c * 5 + piece];
      acc[0] += bf2f((unsigned short)u.x);
      acc[1] += bf2f((unsigned short)(u.x >> 16));
      acc[2] += bf2f((unsigned short)u.y);
      acc[3] += bf2f((unsigned short)(u.y >> 16));
      acc[4] += bf2f((unsigned short)u.z);
      acc[5] += bf2f((unsigned short)(u.z >> 16));
      acc[6] += bf2f((unsigned short)u.w);
      acc[7] += bf2f((unsigned short)(u.w >> 16));
    }
  }
#pragma unroll
  for (int q = 0; q < 8; ++q) {
    float v = acc[q];
    v += __shfl(v, lane + 20, 64);
    v += __shfl(v, lane + 10, 64);
    v += __shfl(v, lane + 5, 64);
    acc[q] = v;
  }
  float inv = 1.f / fmaxf((float)(s1 - s0), 1.f);
  bool owner = lane < 5;
  float v[8];
  float m8 = -1e30f;
  if (owner) {
    const float* rrow = rr + (size_t)row * CLS + lane * 8;
    float4 ra = *(const float4*)rrow;
    float4 rb = *(const float4*)(rrow + 4);
    v[0] = acc[0] * inv + ra.x;
    v[1] = acc[1] * inv + ra.y;
    v[2] = acc[2] * inv + ra.z;
    v[3] = acc[3] * inv + ra.w;
    v[4] = acc[4] * inv + rb.x;
    v[5] = acc[5] * inv + rb.y;
    v[6] = acc[6] * inv + rb.z;
    v[7] = acc[7] * inv + rb.w;
#pragma unroll
    for (int q = 0; q < 8; ++q) m8 = fmaxf(m8, v[q]);
  } else {
#pragma unroll
    for (int q = 0; q < 8; ++q) v[q] = 0.f;
  }
  float mx = -1e30f;
#pragma unroll
  for (int p = 0; p < 5; ++p) mx = fmaxf(mx, __shfl(m8, p, 64));
  float lsum = 0.f;
  if (owner) {
#pragma unroll
    for (int q = 0; q < 8; ++q) lsum += expf(v[q] - mx);
  }
  float sum = 0.f;
#pragma unroll
  for (int p = 0; p < 5; ++p) sum += __shfl(lsum, p, 64);
  float ls = logf(sum);
  if (owner) {
    float* orow = out + (size_t)row * CLS + lane * 8;
    float4 o0, o1;
    o0.x = v[0] - mx - ls;
    o0.y = v[1] - mx - ls;
    o0.z = v[2] - mx - ls;
    o0.w = v[3] - mx - ls;
    o1.x = v[4] - mx - ls;
    o1.y = v[5] - mx - ls;
    o1.z = v[6] - mx - ls;
    o1.w = v[7] - mx - ls;
    *(float4*)orow = o0;
    *(float4*)(orow + 4) = o1;
  }
}

// ---------------- host launcher ----------------
extern "C" void kernel_launch(void* const* d_in, const int* in_sizes, int n_in,
                              void* d_out, int out_size, void* d_ws, size_t ws_size,
                              hipStream_t stream) {
  (void)n_in; (void)out_size; (void)ws_size;
  const float* x   = (const float*)d_in[0];
  const int*   ei  = (const int*)d_in[1];
  const float* W1l = (const float*)d_in[2];
  const float* W1r = (const float*)d_in[3];
  const float* b1  = (const float*)d_in[4];
  const float* W2l = (const float*)d_in[5];
  const float* W2r = (const float*)d_in[6];
  const float* b2  = (const float*)d_in[7];
  float* out = (float*)d_out;

  const int N = in_sizes[0] / F_IN;
  const int E = in_sizes[1] / 2;
  const int Npad = (N + 127) & ~127;
  const int pstep = (N + NPART - 1) / NPART;

  char* ws = (char*)d_ws;
  size_t off = 0;
  auto alloc = [&](size_t bytes) -> void* {
    void* p = ws + off;
    off = (off + bytes + 255) & ~(size_t)255;
    return p;
  };
  int* cnt     = (int*)alloc((size_t)N * 4);
  int* bsum    = (int*)alloc(4096);
  int* rowptr  = (int*)alloc(((size_t)N + 1) * 4);
  int* cursor  = (int*)alloc((size_t)N * 4);
  int* csr_col = (int*)alloc((size_t)E * 4);
  unsigned short* xb   = (unsigned short*)alloc((size_t)Npad * F_IN * 2);
  unsigned short* aggb = (unsigned short*)alloc((size_t)Npad * F_IN * 2);
  unsigned short* W1t  = (unsigned short*)alloc((size_t)256 * 256 * 2);
  unsigned short* W2t  = (unsigned short*)alloc((size_t)80 * 256 * 2);
  unsigned short* hb   = (unsigned short*)alloc((size_t)Npad * HID * 2);
  unsigned short* pp   = (unsigned short*)alloc((size_t)N * CLS * 2);
  float* rr            = (float*)alloc((size_t)N * CLS * 4);

  hipMemsetAsync(cnt, 0, (size_t)N * 4, stream);

  long long n_elems = (long long)Npad * F_IN, n_valid = (long long)N * F_IN;
  // phase A: hist (2048 blocks) || cast_x (1024 blocks)
  phaseA_kernel<<<EDGE_BLOCKS + CASTX_BLOCKS, 256, 0, stream>>>(
      ei, E, cnt, pstep, N, x, (unsigned int*)xb, n_elems, n_valid);

  int nb = (N + 255) / 256;  // 391 <= 512 required by scan_bsum_kernel
  blocksum_kernel<<<nb, 256, 0, stream>>>(cnt, bsum, N);
  scan_bsum_kernel<<<1, 512, 0, stream>>>(bsum, nb);
  scan_apply_kernel<<<nb, 256, 0, stream>>>(cnt, bsum, rowptr, cursor, N, E);

  // phase B: scatter (2048 blocks) || cast_w1 (256) || cast_w2 (80)
  phaseB_kernel<<<EDGE_BLOCKS + 256 + 80, 256, 0, stream>>>(
      ei, E, cursor, csr_col, pstep, N, W1l, W1r, W1t, W2l, W2r, W2t);

  agg1_kernel<<<(N + 3) / 4, 256, 0, stream>>>((const uint4*)xb, rowptr, csr_col,
                                               (uint4*)aggb, N);

  dim3 g1(Npad / 128, 2);
  gemm1_mfma<<<g1, 256, 0, stream>>>(aggb, xb, W1t, b1, hb, N);
  gemm2_mfma<<<Npad / 128, 256, 0, stream>>>(hb, W2t, b2, pp, rr, N);
  final_kernel<<<(N + 3) / 4, 256, 0, stream>>>(rowptr, csr_col, (const uint4*)pp,
                                                rr, out, N);
}